// Round 12
// baseline (165.166 us; speedup 1.0000x reference)
//
#include <hip/hip_runtime.h>

typedef _Float16 half8 __attribute__((ext_vector_type(8)));
typedef _Float16 half4 __attribute__((ext_vector_type(4)));
typedef _Float16 half2 __attribute__((ext_vector_type(2)));
typedef __fp16  fp16x2 __attribute__((ext_vector_type(2)));
typedef float f32x4 __attribute__((ext_vector_type(4)));

static __device__ __forceinline__ half2 cvt_pk(float a, float b) {
    fp16x2 r = __builtin_amdgcn_cvt_pkrtz(a, b);
    return __builtin_bit_cast(half2, r);
}
static __device__ __forceinline__ float fdot2_acc(half2 a, half2 b, float c) {
    return __builtin_amdgcn_fdot2(__builtin_bit_cast(fp16x2, a),
                                  __builtin_bit_cast(fp16x2, b), c, false);
}

// B=8, L1=L2=1024, D_IN=768, H=12, DK=DV=64, M=B*L=8192

// ---------------------------------------------------------------------------
// One-time W transpose+convert: Wt[z][n][k] fp16 = W_z[k][n] fp32, z in {q,k,v}
// ---------------------------------------------------------------------------
__global__ __launch_bounds__(256)
void wtrans_kernel(const float* __restrict__ Wq, const float* __restrict__ Wk,
                   const float* __restrict__ Wv, _Float16* __restrict__ Wt)
{
    __shared__ float t[32][33];
    const float* W = (blockIdx.z == 0) ? Wq : (blockIdx.z == 1) ? Wk : Wv;
    _Float16* dst = Wt + blockIdx.z * 768 * 768;
    const int tx = threadIdx.x & 31, ty = threadIdx.x >> 5;
    const int k0 = blockIdx.y * 32, n0 = blockIdx.x * 32;
    #pragma unroll
    for (int i = 0; i < 4; ++i)
        t[ty + 8 * i][tx] = W[(k0 + ty + 8 * i) * 768 + n0 + tx];
    __syncthreads();
    #pragma unroll
    for (int i = 0; i < 4; ++i)
        dst[(n0 + ty + 8 * i) * 768 + k0 + tx] = (_Float16)t[tx][ty + 8 * i];
}

// ---------------------------------------------------------------------------
// projA: K = y@Wk+bk (z=0) and Q = (x@Wq+bq)/8 (z=1), both row-major fp16.
// 256x128 tile, 8 waves (4m x 2n), double-buffered LDS, 1 barrier/K-step,
// 1-step register prefetch, direct-to-global epilogue (no LDS staging).
// ---------------------------------------------------------------------------
__global__ __launch_bounds__(512, 4)
void projA_kernel(const float* __restrict__ x, const float* __restrict__ y,
                  const _Float16* __restrict__ Wt,
                  const float* __restrict__ bk, const float* __restrict__ bq,
                  _Float16* __restrict__ kout, _Float16* __restrict__ qout)
{
    __shared__ __align__(16) char smem[61440];
    _Float16* const Aa = (_Float16*)smem;                // [256][40]
    _Float16* const Wa = (_Float16*)(smem + 20480);      // [128][40]
    _Float16* const Ab = (_Float16*)(smem + 30720);
    _Float16* const Wb = (_Float16*)(smem + 51200);

    const int tid  = threadIdx.x;
    const int lane = tid & 63;
    const int wave = tid >> 6;
    const int lr = lane & 15, lg = lane >> 4;
    const int wm = wave & 3, wn = wave >> 2;             // 4m x 2n
    const int m0 = blockIdx.x * 256;
    const int n0 = blockIdx.y * 128;
    const int z  = blockIdx.z;                           // 0=K(y) 1=Q(x)

    const float* __restrict__ A = z ? x : y;
    const _Float16* __restrict__ W = Wt + (z ? 0 : 1) * 768 * 768;
    const float* __restrict__ bias = z ? bq : bk;
    _Float16* __restrict__ out = z ? qout : kout;
    const float sc = z ? 0.125f : 1.0f;

    f32x4 acc[4][4] = {};

    const int ar = tid >> 3;           // 0..63 (4 strips of 64)
    const int ac = (tid & 7) * 4;      // A col (of 32 fp32)
    const int wrow = tid >> 2;         // 0..127
    const int wc   = (tid & 3) * 8;    // halves

    const float* const Ag = A + (m0 + ar) * 768 + ac;
    const _Float16* const Wg = W + (n0 + wrow) * 768 + wc;

    float4 ra0, ra1, ra2, ra3;
    uint4 rw0;
    auto load_regs = [&](int kb) {
        ra0 = *(const float4*)(Ag + kb * 32);
        ra1 = *(const float4*)(Ag + kb * 32 + 64 * 768);
        ra2 = *(const float4*)(Ag + kb * 32 + 128 * 768);
        ra3 = *(const float4*)(Ag + kb * 32 + 192 * 768);
        rw0 = *(const uint4*)(Wg + kb * 32);
    };

    auto step = [&](int kb, _Float16* Ad, _Float16* Wd) {
        union { half2 hh[2]; half4 v; } c0, c1, c2, c3;
        c0.hh[0] = cvt_pk(ra0.x, ra0.y); c0.hh[1] = cvt_pk(ra0.z, ra0.w);
        c1.hh[0] = cvt_pk(ra1.x, ra1.y); c1.hh[1] = cvt_pk(ra1.z, ra1.w);
        c2.hh[0] = cvt_pk(ra2.x, ra2.y); c2.hh[1] = cvt_pk(ra2.z, ra2.w);
        c3.hh[0] = cvt_pk(ra3.x, ra3.y); c3.hh[1] = cvt_pk(ra3.z, ra3.w);
        *(half4*)(Ad + ar * 40 + ac)           = c0.v;
        *(half4*)(Ad + (ar + 64) * 40 + ac)    = c1.v;
        *(half4*)(Ad + (ar + 128) * 40 + ac)   = c2.v;
        *(half4*)(Ad + (ar + 192) * 40 + ac)   = c3.v;
        *(uint4*)(Wd + wrow * 40 + wc)         = rw0;
        if (kb < 23) load_regs(kb + 1);
        __syncthreads();
        // Race-freedom: next write to this buffer is at step kb+2, reached
        // only after barrier(kb+1), which postdates every wave's compute(kb).
        half8 af[4], bf[4];
        #pragma unroll
        for (int mt = 0; mt < 4; ++mt)
            af[mt] = *(const half8*)(Ad + (wm * 64 + mt * 16 + lr) * 40 + lg * 8);
        #pragma unroll
        for (int nt = 0; nt < 4; ++nt)
            bf[nt] = *(const half8*)(Wd + (wn * 64 + nt * 16 + lr) * 40 + lg * 8);
        __builtin_amdgcn_s_setprio(1);
        #pragma unroll
        for (int mt = 0; mt < 4; ++mt)
            #pragma unroll
            for (int nt = 0; nt < 4; ++nt)
                acc[mt][nt] = __builtin_amdgcn_mfma_f32_16x16x32_f16(af[mt], bf[nt], acc[mt][nt], 0, 0, 0);
        __builtin_amdgcn_s_setprio(0);
    };

    load_regs(0);
    for (int j = 0; j < 12; ++j) {
        step(2 * j,     Aa, Wa);
        step(2 * j + 1, Ab, Wb);
    }

    // direct epilogue: out[row][col], col coalesced across lr (32B segments)
    #pragma unroll
    for (int nt = 0; nt < 4; ++nt) {
        const int col = n0 + wn * 64 + nt * 16 + lr;
        const float bs = bias[col];
        #pragma unroll
        for (int mt = 0; mt < 4; ++mt) {
            const int row = m0 + wm * 64 + mt * 16 + lg * 4;
            #pragma unroll
            for (int r = 0; r < 4; ++r)
                out[(row + r) * 768 + col] = (_Float16)((acc[mt][nt][r] + bs) * sc);
        }
    }
}

// ---------------------------------------------------------------------------
// projV: V = y@Wv+bv -> Vt [B][H*DV][L2] (transposed epilogue via LDS).
// 128x128 tile, double-buffered, 1 barrier/K-step (r11 structure).
// ---------------------------------------------------------------------------
__global__ __launch_bounds__(256)
void projV_kernel(const float* __restrict__ y, const _Float16* __restrict__ Wt,
                  const float* __restrict__ bv, _Float16* __restrict__ vout)
{
    __shared__ __align__(16) char smem[40960];
    _Float16* const Aa = (_Float16*)smem;                // [128][40]
    _Float16* const Wa = (_Float16*)(smem + 10240);      // [128][40]
    _Float16* const Ab = (_Float16*)(smem + 20480);
    _Float16* const Wb = (_Float16*)(smem + 30720);
    _Float16* const Tlds = (_Float16*)smem;              // [128][136] epilogue

    const int tid  = threadIdx.x;
    const int lane = tid & 63;
    const int wave = tid >> 6;
    const int lr = lane & 15, lg = lane >> 4;
    const int wm = wave >> 1, wn = wave & 1;
    const int m0 = blockIdx.x * 128;
    const int n0 = blockIdx.y * 128;

    const _Float16* __restrict__ W = Wt + 2 * 768 * 768;

    f32x4 acc[4][4] = {};

    const int ar  = tid >> 3;
    const int ac  = (tid & 7) * 4;
    const int wrow = tid >> 1;
    const int wcb  = (tid & 1) * 16;

    const float* const Ag = y + (m0 + ar) * 768 + ac;
    const _Float16* const Wg = W + (n0 + wrow) * 768 + wcb;

    float4 ra0, ra1, ra2, ra3;
    uint4 rw0, rw1;
    auto load_regs = [&](int kb) {
        ra0 = *(const float4*)(Ag + kb * 32);
        ra1 = *(const float4*)(Ag + kb * 32 + 32 * 768);
        ra2 = *(const float4*)(Ag + kb * 32 + 64 * 768);
        ra3 = *(const float4*)(Ag + kb * 32 + 96 * 768);
        rw0 = *(const uint4*)(Wg + kb * 32);
        rw1 = *(const uint4*)(Wg + kb * 32 + 8);
    };

    auto step = [&](int kb, _Float16* Ad, _Float16* Wd) {
        union { half2 hh[2]; half4 v; } c0, c1, c2, c3;
        c0.hh[0] = cvt_pk(ra0.x, ra0.y); c0.hh[1] = cvt_pk(ra0.z, ra0.w);
        c1.hh[0] = cvt_pk(ra1.x, ra1.y); c1.hh[1] = cvt_pk(ra1.z, ra1.w);
        c2.hh[0] = cvt_pk(ra2.x, ra2.y); c2.hh[1] = cvt_pk(ra2.z, ra2.w);
        c3.hh[0] = cvt_pk(ra3.x, ra3.y); c3.hh[1] = cvt_pk(ra3.z, ra3.w);
        *(half4*)(Ad + ar * 40 + ac)          = c0.v;
        *(half4*)(Ad + (ar + 32) * 40 + ac)   = c1.v;
        *(half4*)(Ad + (ar + 64) * 40 + ac)   = c2.v;
        *(half4*)(Ad + (ar + 96) * 40 + ac)   = c3.v;
        *(uint4*)(Wd + wrow * 40 + wcb)       = rw0;
        *(uint4*)(Wd + wrow * 40 + wcb + 8)   = rw1;
        if (kb < 23) load_regs(kb + 1);
        __syncthreads();
        half8 af[4], bf[4];
        #pragma unroll
        for (int mt = 0; mt < 4; ++mt)
            af[mt] = *(const half8*)(Ad + (wm * 64 + mt * 16 + lr) * 40 + lg * 8);
        #pragma unroll
        for (int nt = 0; nt < 4; ++nt)
            bf[nt] = *(const half8*)(Wd + (wn * 64 + nt * 16 + lr) * 40 + lg * 8);
        __builtin_amdgcn_s_setprio(1);
        #pragma unroll
        for (int mt = 0; mt < 4; ++mt)
            #pragma unroll
            for (int nt = 0; nt < 4; ++nt)
                acc[mt][nt] = __builtin_amdgcn_mfma_f32_16x16x32_f16(af[mt], bf[nt], acc[mt][nt], 0, 0, 0);
        __builtin_amdgcn_s_setprio(0);
    };

    load_regs(0);
    for (int j = 0; j < 12; ++j) {
        step(2 * j,     Aa, Wa);
        step(2 * j + 1, Ab, Wb);
    }

    __syncthreads();   // Tlds aliases the K-loop buffers
    #pragma unroll
    for (int nt = 0; nt < 4; ++nt) {
        const int col = wn * 64 + nt * 16 + lr;
        const float bs = bv[n0 + col];
        #pragma unroll
        for (int mt = 0; mt < 4; ++mt) {
            #pragma unroll
            for (int r = 0; r < 4; ++r) {
                const int row = wm * 64 + mt * 16 + lg * 4 + r;
                Tlds[col * 136 + row] = (_Float16)(acc[mt][nt][r] + bs);
            }
        }
    }
    __syncthreads();

    const int crow = tid >> 1;
    const int cb   = (tid & 1) * 64;
    const _Float16* lsrc = Tlds + crow * 136 + cb;
    const int bb  = m0 >> 10;
    const int l2b = m0 & 1023;
    _Float16* gdst = vout + (bb * 768 + n0 + crow) * 1024 + l2b + cb;
    #pragma unroll
    for (int it = 0; it < 8; ++it)
        *(uint4*)(gdst + it * 8) = *(const uint4*)(lsrc + it * 8);
}

// ---------------------------------------------------------------------------
// Fused attention, per block (q-tile=64, h, b).
// QPRE=1: Q precomputed in ws. QPRE=0: phase-1 Q projection (fallback).
// Phase 2: flash loop, KVBLK=64, double-buffered LDS (1 barrier/tile),
//          2-tile-deep register prefetch, exp2 softmax, defer-max.
// ---------------------------------------------------------------------------
template<bool QPRE>
__global__ __launch_bounds__(256)
void attn_kernel(const float* __restrict__ x, const _Float16* __restrict__ Wtq,
                 const float* __restrict__ bq, const _Float16* __restrict__ Qp,
                 const _Float16* __restrict__ K, const _Float16* __restrict__ Vt,
                 const unsigned char* __restrict__ mask,
                 float* __restrict__ out)
{
    __shared__ __align__(16) char smem[48128];
    _Float16* const KA = (_Float16*)smem;              // K buf A [64][72]
    _Float16* const KB = (_Float16*)(smem + 9216);     // K buf B
    _Float16* const VA = (_Float16*)(smem + 18432);    // V buf A
    _Float16* const VB = (_Float16*)(smem + 27648);    // V buf B
    _Float16* const QP = (_Float16*)(smem + 36864);    // Q [64][72] -> per-wave P
    _Float16* const Mh = (_Float16*)(smem + 46080);    // [1024] fp16 0/1

    const int tid  = threadIdx.x;
    const int lane = tid & 63;
    const int wave = tid >> 6;
    const int lr = lane & 15, lg = lane >> 4;
    const int q0 = blockIdx.x * 64;
    const int h  = blockIdx.y;
    const int b  = blockIdx.z;

    const int pr = tid >> 2;            // 0..63 staging row
    const int pc = (tid & 3) * 16;      // staging col (16 halves)

    const float C2 = 1.44269504f;       // log2(e)

    if constexpr (!QPRE) {
        const float* xbase = x + (b * 1024 + q0 + pr) * 768 + pc;
        const _Float16* wbase = Wtq + (h * 64 + pr) * 768 + pc;
        float4 xa, xb, xc_, xd;
        uint4 wa, wb;
        xa = *(const float4*)(xbase);      xb = *(const float4*)(xbase + 4);
        xc_ = *(const float4*)(xbase + 8); xd = *(const float4*)(xbase + 12);
        wa = *(const uint4*)(wbase);       wb = *(const uint4*)(wbase + 8);

        f32x4 qacc[4] = {};
        for (int kb = 0; kb < 12; ++kb) {
            __syncthreads();
            union { half2 hh[4]; half8 v; } u0, u1;
            u0.hh[0] = cvt_pk(xa.x, xa.y);   u0.hh[1] = cvt_pk(xa.z, xa.w);
            u0.hh[2] = cvt_pk(xb.x, xb.y);   u0.hh[3] = cvt_pk(xb.z, xb.w);
            u1.hh[0] = cvt_pk(xc_.x, xc_.y); u1.hh[1] = cvt_pk(xc_.z, xc_.w);
            u1.hh[2] = cvt_pk(xd.x, xd.y);   u1.hh[3] = cvt_pk(xd.z, xd.w);
            *(half8*)(KA + pr * 72 + pc)     = u0.v;
            *(half8*)(KA + pr * 72 + pc + 8) = u1.v;
            *(uint4*)(VA + pr * 72 + pc)     = wa;
            *(uint4*)(VA + pr * 72 + pc + 8) = wb;
            __syncthreads();
            if (kb < 11) {
                const float* xn = xbase + (kb + 1) * 64;
                const _Float16* wn = wbase + (kb + 1) * 64;
                xa = *(const float4*)(xn);      xb = *(const float4*)(xn + 4);
                xc_ = *(const float4*)(xn + 8); xd = *(const float4*)(xn + 12);
                wa = *(const uint4*)(wn);       wb = *(const uint4*)(wn + 8);
            }
            half8 af[2];
            af[0] = *(const half8*)(KA + (wave * 16 + lr) * 72 + lg * 8);
            af[1] = *(const half8*)(KA + (wave * 16 + lr) * 72 + 32 + lg * 8);
            __builtin_amdgcn_s_setprio(1);
            #pragma unroll
            for (int nt = 0; nt < 4; ++nt)
                #pragma unroll
                for (int s = 0; s < 2; ++s) {
                    const half8 bf = *(const half8*)(VA + (nt * 16 + lr) * 72 + s * 32 + lg * 8);
                    qacc[nt] = __builtin_amdgcn_mfma_f32_16x16x32_f16(af[s], bf, qacc[nt], 0, 0, 0);
                }
            __builtin_amdgcn_s_setprio(0);
        }
        #pragma unroll
        for (int nt = 0; nt < 4; ++nt) {
            const int d = nt * 16 + lr;
            const float bs = bq[h * 64 + d];
            #pragma unroll
            for (int r = 0; r < 4; ++r)
                QP[(wave * 16 + lg * 4 + r) * 72 + d] = (_Float16)((qacc[nt][r] + bs) * 0.125f);
        }
    }

    {
        const uchar4 mk = *(const uchar4*)(mask + b * 1024 + tid * 4);
        half4 mh = { mk.x ? (_Float16)0.f : (_Float16)1.f,
                     mk.y ? (_Float16)0.f : (_Float16)1.f,
                     mk.z ? (_Float16)0.f : (_Float16)1.f,
                     mk.w ? (_Float16)0.f : (_Float16)1.f };
        *(half4*)(Mh + tid * 4) = mh;
    }
    __syncthreads();

    half8 qf[2];
    if constexpr (QPRE) {
        const _Float16* qrp = Qp + (b * 1024 + q0 + wave * 16 + lr) * 768 + h * 64;
        qf[0] = *(const half8*)(qrp + lg * 8);
        qf[1] = *(const half8*)(qrp + 32 + lg * 8);
    } else {
        qf[0] = *(const half8*)(QP + (wave * 16 + lr) * 72 + lg * 8);
        qf[1] = *(const half8*)(QP + (wave * 16 + lr) * 72 + 32 + lg * 8);
    }

    f32x4 o[4] = {};
    float m_run = -1e30f, l_run = 0.f;
    const half2 one2 = { (_Float16)1.f, (_Float16)1.f };

    const _Float16* const Kg = K + (b * 1024 + pr) * 768 + h * 64 + pc;
    const _Float16* const Vg = Vt + (b * 768 + h * 64 + pr) * 1024 + pc;
    _Float16* const Pw = QP + wave * 1152;

    auto compute = [&](int kv0, const _Float16* Kb, const _Float16* Vb) {
        f32x4 st[4] = {};
        __builtin_amdgcn_s_setprio(1);
        #pragma unroll
        for (int t4 = 0; t4 < 4; ++t4)
            #pragma unroll
            for (int s = 0; s < 2; ++s) {
                const half8 a = *(const half8*)(Kb + (t4 * 16 + lr) * 72 + s * 32 + lg * 8);
                st[t4] = __builtin_amdgcn_mfma_f32_16x16x32_f16(a, qf[s], st[t4], 0, 0, 0);
            }
        __builtin_amdgcn_s_setprio(0);

        float mx = fmaxf(
            fmaxf(fmaxf(fmaxf(st[0][0], st[0][1]), fmaxf(st[0][2], st[0][3])),
                  fmaxf(fmaxf(st[1][0], st[1][1]), fmaxf(st[1][2], st[1][3]))),
            fmaxf(fmaxf(fmaxf(st[2][0], st[2][1]), fmaxf(st[2][2], st[2][3])),
                  fmaxf(fmaxf(st[3][0], st[3][1]), fmaxf(st[3][2], st[3][3]))));
        mx = fmaxf(mx, __shfl_xor(mx, 16));
        mx = fmaxf(mx, __shfl_xor(mx, 32));

        if (!__all(mx <= m_run + 8.f)) {
            const float m_new = fmaxf(m_run, mx);
            const float corr = __builtin_amdgcn_exp2f((m_run - m_new) * C2);
            l_run *= corr;
            #pragma unroll
            for (int i = 0; i < 4; ++i) o[i] *= corr;
            m_run = m_new;
        }
        const float nb = -m_run * C2;

        float ps = 0.f;
        #pragma unroll
        for (int t4 = 0; t4 < 4; ++t4) {
            half2 pa = cvt_pk(__builtin_amdgcn_exp2f(fmaf(st[t4][0], C2, nb)),
                              __builtin_amdgcn_exp2f(fmaf(st[t4][1], C2, nb)));
            half2 pb = cvt_pk(__builtin_amdgcn_exp2f(fmaf(st[t4][2], C2, nb)),
                              __builtin_amdgcn_exp2f(fmaf(st[t4][3], C2, nb)));
            const half4 mv = *(const half4*)(Mh + kv0 + t4 * 16 + lg * 4);
            const half2 mk0 = { mv[0], mv[1] };
            const half2 mk1 = { mv[2], mv[3] };
            pa *= mk0;
            pb *= mk1;
            ps = fdot2_acc(pa, one2, ps);
            ps = fdot2_acc(pb, one2, ps);
            union { half2 hh[2]; half4 v; } pk;
            pk.hh[0] = pa; pk.hh[1] = pb;
            *(half4*)(Pw + lr * 72 + t4 * 16 + lg * 4) = pk.v;
        }
        ps += __shfl_xor(ps, 16);
        ps += __shfl_xor(ps, 32);
        l_run += ps;

        asm volatile("s_waitcnt lgkmcnt(0)" ::: "memory");
        __builtin_amdgcn_sched_barrier(0);

        half8 pf[2];
        pf[0] = *(const half8*)(Pw + lr * 72 + lg * 8);
        pf[1] = *(const half8*)(Pw + lr * 72 + 32 + lg * 8);

        __builtin_amdgcn_s_setprio(1);
        #pragma unroll
        for (int dt = 0; dt < 4; ++dt)
            #pragma unroll
            for (int ks = 0; ks < 2; ++ks) {
                const half8 a = *(const half8*)(Vb + (dt * 16 + lr) * 72 + ks * 32 + lg * 8);
                o[dt] = __builtin_amdgcn_mfma_f32_16x16x32_f16(a, pf[ks], o[dt], 0, 0, 0);
            }
        __builtin_amdgcn_s_setprio(0);
    };

    uint4 ka0, ka1, va0, va1, kb0, kb1, vb0, vb1;
    ka0 = *(const uint4*)(Kg);            ka1 = *(const uint4*)(Kg + 8);
    va0 = *(const uint4*)(Vg);            va1 = *(const uint4*)(Vg + 8);
    kb0 = *(const uint4*)(Kg + 64 * 768); kb1 = *(const uint4*)(Kg + 64 * 768 + 8);
    vb0 = *(const uint4*)(Vg + 64);       vb1 = *(const uint4*)(Vg + 64 + 8);

    for (int j = 0; j < 8; ++j) {
        *(uint4*)(KA + pr * 72 + pc)     = ka0;
        *(uint4*)(KA + pr * 72 + pc + 8) = ka1;
        *(uint4*)(VA + pr * 72 + pc)     = va0;
        *(uint4*)(VA + pr * 72 + pc + 8) = va1;
        if (j < 7) {
            const int t = (2 * j + 2) * 64;
            ka0 = *(const uint4*)(Kg + t * 768);
            ka1 = *(const uint4*)(Kg + t * 768 + 8);
            va0 = *(const uint4*)(Vg + t);
            va1 = *(const uint4*)(Vg + t + 8);
        }
        __syncthreads();
        compute(2 * j * 64, KA, VA);

        *(uint4*)(KB + pr * 72 + pc)     = kb0;
        *(uint4*)(KB + pr * 72 + pc + 8) = kb1;
        *(uint4*)(VB + pr * 72 + pc)     = vb0;
        *(uint4*)(VB + pr * 72 + pc + 8) = vb1;
        if (j < 7) {
            const int t = (2 * j + 3) * 64;
            kb0 = *(const uint4*)(Kg + t * 768);
            kb1 = *(const uint4*)(Kg + t * 768 + 8);
            vb0 = *(const uint4*)(Vg + t);
            vb1 = *(const uint4*)(Vg + t + 8);
        }
        __syncthreads();
        compute((2 * j + 1) * 64, KB, VB);
    }

    const float inv = 1.f / l_run;
    const int qrow = b * 1024 + q0 + wave * 16 + lr;
    float* od = out + qrow * 768 + h * 64 + lg * 4;
    #pragma unroll
    for (int dt = 0; dt < 4; ++dt) {
        float4 v;
        v.x = o[dt][0] * inv; v.y = o[dt][1] * inv;
        v.z = o[dt][2] * inv; v.w = o[dt][3] * inv;
        *(float4*)(od + dt * 16) = v;
    }
}

extern "C" void kernel_launch(void* const* d_in, const int* in_sizes, int n_in,
                              void* d_out, int out_size, void* d_ws, size_t ws_size,
                              hipStream_t stream)
{
    const float* x  = (const float*)d_in[0];
    const float* y  = (const float*)d_in[1];
    const unsigned char* ym = (const unsigned char*)d_in[2];
    const float* Wq = (const float*)d_in[3];
    const float* bq = (const float*)d_in[4];
    const float* Wk = (const float*)d_in[5];
    const float* bk = (const float*)d_in[6];
    const float* Wv = (const float*)d_in[7];
    const float* bv = (const float*)d_in[8];

    _Float16* kws = (_Float16*)d_ws;             // [8192][768] K
    _Float16* vws = kws + 8192 * 768;            // [B][H*DV][L2] V^T
    _Float16* wt  = vws + 8192 * 768;            // [3][768][768] W^T (q,k,v)
    _Float16* qws = wt + 3 * 768 * 768;          // [8192][768] Q (optional)

    const size_t need = (size_t)(3 * 8192 * 768 + 3 * 768 * 768) * sizeof(_Float16);
    const bool qpre = ws_size >= need;

    wtrans_kernel<<<dim3(24, 24, 3), 256, 0, stream>>>(Wq, Wk, Wv, wt);
    if (qpre) {
        projA_kernel<<<dim3(32, 6, 2), 512, 0, stream>>>(x, y, wt, bk, bq, kws, qws);
        projV_kernel<<<dim3(64, 6), 256, 0, stream>>>(y, wt, bv, vws);
        attn_kernel<true><<<dim3(16, 12, 8), 256, 0, stream>>>(
            x, wt, bq, qws, kws, vws, ym, (float*)d_out);
    } else {
        projA_kernel<<<dim3(32, 6, 1), 512, 0, stream>>>(x, y, wt, bk, bq, kws, qws);
        projV_kernel<<<dim3(64, 6), 256, 0, stream>>>(y, wt, bv, vws);
        attn_kernel<false><<<dim3(16, 12, 8), 256, 0, stream>>>(
            x, wt, bq, qws, kws, vws, ym, (float*)d_out);
    }
}

// Round 13
// 138.842 us; speedup vs baseline: 1.1896x; 1.1896x over previous
//
#include <hip/hip_runtime.h>

typedef _Float16 half8 __attribute__((ext_vector_type(8)));
typedef _Float16 half4 __attribute__((ext_vector_type(4)));
typedef _Float16 half2 __attribute__((ext_vector_type(2)));
typedef __fp16  fp16x2 __attribute__((ext_vector_type(2)));
typedef float f32x4 __attribute__((ext_vector_type(4)));

static __device__ __forceinline__ half2 cvt_pk(float a, float b) {
    fp16x2 r = __builtin_amdgcn_cvt_pkrtz(a, b);
    return __builtin_bit_cast(half2, r);
}
static __device__ __forceinline__ float fdot2_acc(half2 a, half2 b, float c) {
    return __builtin_amdgcn_fdot2(__builtin_bit_cast(fp16x2, a),
                                  __builtin_bit_cast(fp16x2, b), c, false);
}

// B=8, L1=L2=1024, D_IN=768, H=12, DK=DV=64, M=B*L=8192

// ---------------------------------------------------------------------------
// One-time W transpose+convert: Wt[z][n][k] fp16 = W_z[k][n] fp32, z in {q,k,v}
// ---------------------------------------------------------------------------
__global__ __launch_bounds__(256)
void wtrans_kernel(const float* __restrict__ Wq, const float* __restrict__ Wk,
                   const float* __restrict__ Wv, _Float16* __restrict__ Wt)
{
    __shared__ float t[32][33];
    const float* W = (blockIdx.z == 0) ? Wq : (blockIdx.z == 1) ? Wk : Wv;
    _Float16* dst = Wt + blockIdx.z * 768 * 768;
    const int tx = threadIdx.x & 31, ty = threadIdx.x >> 5;
    const int k0 = blockIdx.y * 32, n0 = blockIdx.x * 32;
    #pragma unroll
    for (int i = 0; i < 4; ++i)
        t[ty + 8 * i][tx] = W[(k0 + ty + 8 * i) * 768 + n0 + tx];
    __syncthreads();
    #pragma unroll
    for (int i = 0; i < 4; ++i)
        dst[(n0 + ty + 8 * i) * 768 + k0 + tx] = (_Float16)t[tx][ty + 8 * i];
}

// ---------------------------------------------------------------------------
// projKV (r9-verbatim structure): z=0: K = y@Wk+bk -> [8192][768]
//                                 z=1: V = y@Wv+bv -> Vt [B][H*DV][L2]
// ---------------------------------------------------------------------------
__global__ __launch_bounds__(256)
void projKV_kernel(const float* __restrict__ A, const _Float16* __restrict__ Wt,
                   const float* __restrict__ bk, const float* __restrict__ bv,
                   _Float16* __restrict__ kout, _Float16* __restrict__ vout)
{
    __shared__ __align__(16) char smem[34816];
    _Float16* const Alds = (_Float16*)smem;            // [128][40] padded
    _Float16* const Wlds = (_Float16*)smem + 128 * 40; // [128][40]
    _Float16* const Tlds = (_Float16*)smem;            // [128][136] epilogue

    const int tid  = threadIdx.x;
    const int lane = tid & 63;
    const int wave = tid >> 6;
    const int lr = lane & 15, lg = lane >> 4;
    const int wm = wave >> 1, wn = wave & 1;
    const int m0 = blockIdx.x * 128;
    const int n0 = blockIdx.y * 128;
    const int isv = blockIdx.z;

    const _Float16* __restrict__ W = Wt + (1 + isv) * 768 * 768;
    const float* __restrict__ bias = isv ? bv : bk;

    f32x4 acc[4][4] = {};

    const int ar   = tid >> 3;
    const int ac   = (tid & 7) * 4;
    const int wrow = tid >> 1;
    const int wcb  = (tid & 1) * 16;

    for (int kb = 0; kb < 24; ++kb) {
        #pragma unroll
        for (int i = 0; i < 4; ++i) {
            const int row = ar + 32 * i;
            const float4 v = *(const float4*)(A + (m0 + row) * 768 + kb * 32 + ac);
            half4 hh = { (_Float16)v.x, (_Float16)v.y, (_Float16)v.z, (_Float16)v.w };
            *(half4*)(Alds + row * 40 + ac) = hh;
        }
        {
            const _Float16* wtr = W + (n0 + wrow) * 768 + kb * 32 + wcb;
            *(uint4*)(Wlds + wrow * 40 + wcb)     = *(const uint4*)(wtr);
            *(uint4*)(Wlds + wrow * 40 + wcb + 8) = *(const uint4*)(wtr + 8);
        }
        __syncthreads();

        half8 af[4], bf[4];
        #pragma unroll
        for (int mt = 0; mt < 4; ++mt)
            af[mt] = *(const half8*)(Alds + (wm * 64 + mt * 16 + lr) * 40 + lg * 8);
        #pragma unroll
        for (int nt = 0; nt < 4; ++nt)
            bf[nt] = *(const half8*)(Wlds + (wn * 64 + nt * 16 + lr) * 40 + lg * 8);
        #pragma unroll
        for (int mt = 0; mt < 4; ++mt)
            #pragma unroll
            for (int nt = 0; nt < 4; ++nt)
                acc[mt][nt] = __builtin_amdgcn_mfma_f32_16x16x32_f16(af[mt], bf[nt], acc[mt][nt], 0, 0, 0);
        __syncthreads();
    }

    #pragma unroll
    for (int nt = 0; nt < 4; ++nt) {
        const int col = wn * 64 + nt * 16 + lr;
        const float bs = bias[n0 + col];
        #pragma unroll
        for (int mt = 0; mt < 4; ++mt) {
            #pragma unroll
            for (int r = 0; r < 4; ++r) {
                const int row = wm * 64 + mt * 16 + lg * 4 + r;
                const float val = acc[mt][nt][r] + bs;
                if (isv) Tlds[col * 136 + row] = (_Float16)val;
                else     Tlds[row * 136 + col] = (_Float16)val;
            }
        }
    }
    __syncthreads();

    const int crow = tid >> 1;
    const int cb   = (tid & 1) * 64;
    const _Float16* lsrc = Tlds + crow * 136 + cb;
    _Float16* gdst;
    if (isv) {
        const int bb  = m0 >> 10;
        const int l2b = m0 & 1023;
        gdst = vout + (bb * 768 + n0 + crow) * 1024 + l2b + cb;
    } else {
        gdst = kout + (m0 + crow) * 768 + n0 + cb;
    }
    #pragma unroll
    for (int it = 0; it < 8; ++it)
        *(uint4*)(gdst + it * 8) = *(const uint4*)(lsrc + it * 8);
}

// ---------------------------------------------------------------------------
// projQ (same structure, own dispatch): Q = (x@Wq+bq)*0.125 -> [8192][768]
// ---------------------------------------------------------------------------
__global__ __launch_bounds__(256)
void projQ_kernel(const float* __restrict__ x, const _Float16* __restrict__ Wt,
                  const float* __restrict__ bq, _Float16* __restrict__ qout)
{
    __shared__ __align__(16) char smem[34816];
    _Float16* const Alds = (_Float16*)smem;            // [128][40]
    _Float16* const Wlds = (_Float16*)smem + 128 * 40; // [128][40]
    _Float16* const Tlds = (_Float16*)smem;            // [128][136]

    const int tid  = threadIdx.x;
    const int lane = tid & 63;
    const int wave = tid >> 6;
    const int lr = lane & 15, lg = lane >> 4;
    const int wm = wave >> 1, wn = wave & 1;
    const int m0 = blockIdx.x * 128;
    const int n0 = blockIdx.y * 128;

    const _Float16* __restrict__ W = Wt;               // q slice

    f32x4 acc[4][4] = {};

    const int ar   = tid >> 3;
    const int ac   = (tid & 7) * 4;
    const int wrow = tid >> 1;
    const int wcb  = (tid & 1) * 16;

    for (int kb = 0; kb < 24; ++kb) {
        #pragma unroll
        for (int i = 0; i < 4; ++i) {
            const int row = ar + 32 * i;
            const float4 v = *(const float4*)(x + (m0 + row) * 768 + kb * 32 + ac);
            half4 hh = { (_Float16)v.x, (_Float16)v.y, (_Float16)v.z, (_Float16)v.w };
            *(half4*)(Alds + row * 40 + ac) = hh;
        }
        {
            const _Float16* wtr = W + (n0 + wrow) * 768 + kb * 32 + wcb;
            *(uint4*)(Wlds + wrow * 40 + wcb)     = *(const uint4*)(wtr);
            *(uint4*)(Wlds + wrow * 40 + wcb + 8) = *(const uint4*)(wtr + 8);
        }
        __syncthreads();

        half8 af[4], bf[4];
        #pragma unroll
        for (int mt = 0; mt < 4; ++mt)
            af[mt] = *(const half8*)(Alds + (wm * 64 + mt * 16 + lr) * 40 + lg * 8);
        #pragma unroll
        for (int nt = 0; nt < 4; ++nt)
            bf[nt] = *(const half8*)(Wlds + (wn * 64 + nt * 16 + lr) * 40 + lg * 8);
        #pragma unroll
        for (int mt = 0; mt < 4; ++mt)
            #pragma unroll
            for (int nt = 0; nt < 4; ++nt)
                acc[mt][nt] = __builtin_amdgcn_mfma_f32_16x16x32_f16(af[mt], bf[nt], acc[mt][nt], 0, 0, 0);
        __syncthreads();
    }

    #pragma unroll
    for (int nt = 0; nt < 4; ++nt) {
        const int col = wn * 64 + nt * 16 + lr;
        const float bs = bq[n0 + col];
        #pragma unroll
        for (int mt = 0; mt < 4; ++mt) {
            #pragma unroll
            for (int r = 0; r < 4; ++r) {
                const int row = wm * 64 + mt * 16 + lg * 4 + r;
                Tlds[row * 136 + col] = (_Float16)((acc[mt][nt][r] + bs) * 0.125f);
            }
        }
    }
    __syncthreads();

    const int crow = tid >> 1;
    const int cb   = (tid & 1) * 64;
    const _Float16* lsrc = Tlds + crow * 136 + cb;
    _Float16* gdst = qout + (m0 + crow) * 768 + n0 + cb;
    #pragma unroll
    for (int it = 0; it < 8; ++it)
        *(uint4*)(gdst + it * 8) = *(const uint4*)(lsrc + it * 8);
}

// ---------------------------------------------------------------------------
// Fused attention, per block (q-tile=64, h, b).
// QPRE=1: Q precomputed in ws. QPRE=0: phase-1 Q projection (fallback).
// Phase 2: flash loop, KVBLK=64, double-buffered LDS (1 barrier/tile),
//          2-tile-deep register prefetch, exp2 softmax, defer-max.
// ---------------------------------------------------------------------------
template<bool QPRE>
__global__ __launch_bounds__(256)
void attn_kernel(const float* __restrict__ x, const _Float16* __restrict__ Wtq,
                 const float* __restrict__ bq, const _Float16* __restrict__ Qp,
                 const _Float16* __restrict__ K, const _Float16* __restrict__ Vt,
                 const unsigned char* __restrict__ mask,
                 float* __restrict__ out)
{
    __shared__ __align__(16) char smem[48128];
    _Float16* const KA = (_Float16*)smem;              // K buf A [64][72]
    _Float16* const KB = (_Float16*)(smem + 9216);     // K buf B
    _Float16* const VA = (_Float16*)(smem + 18432);    // V buf A
    _Float16* const VB = (_Float16*)(smem + 27648);    // V buf B
    _Float16* const QP = (_Float16*)(smem + 36864);    // Q [64][72] -> per-wave P
    _Float16* const Mh = (_Float16*)(smem + 46080);    // [1024] fp16 0/1

    const int tid  = threadIdx.x;
    const int lane = tid & 63;
    const int wave = tid >> 6;
    const int lr = lane & 15, lg = lane >> 4;
    const int q0 = blockIdx.x * 64;
    const int h  = blockIdx.y;
    const int b  = blockIdx.z;

    const int pr = tid >> 2;            // 0..63 staging row
    const int pc = (tid & 3) * 16;      // staging col (16 halves)

    const float C2 = 1.44269504f;       // log2(e)

    if constexpr (!QPRE) {
        const float* xbase = x + (b * 1024 + q0 + pr) * 768 + pc;
        const _Float16* wbase = Wtq + (h * 64 + pr) * 768 + pc;
        float4 xa, xb, xc_, xd;
        uint4 wa, wb;
        xa = *(const float4*)(xbase);      xb = *(const float4*)(xbase + 4);
        xc_ = *(const float4*)(xbase + 8); xd = *(const float4*)(xbase + 12);
        wa = *(const uint4*)(wbase);       wb = *(const uint4*)(wbase + 8);

        f32x4 qacc[4] = {};
        for (int kb = 0; kb < 12; ++kb) {
            __syncthreads();
            union { half2 hh[4]; half8 v; } u0, u1;
            u0.hh[0] = cvt_pk(xa.x, xa.y);   u0.hh[1] = cvt_pk(xa.z, xa.w);
            u0.hh[2] = cvt_pk(xb.x, xb.y);   u0.hh[3] = cvt_pk(xb.z, xb.w);
            u1.hh[0] = cvt_pk(xc_.x, xc_.y); u1.hh[1] = cvt_pk(xc_.z, xc_.w);
            u1.hh[2] = cvt_pk(xd.x, xd.y);   u1.hh[3] = cvt_pk(xd.z, xd.w);
            *(half8*)(KA + pr * 72 + pc)     = u0.v;
            *(half8*)(KA + pr * 72 + pc + 8) = u1.v;
            *(uint4*)(VA + pr * 72 + pc)     = wa;
            *(uint4*)(VA + pr * 72 + pc + 8) = wb;
            __syncthreads();
            if (kb < 11) {
                const float* xn = xbase + (kb + 1) * 64;
                const _Float16* wn = wbase + (kb + 1) * 64;
                xa = *(const float4*)(xn);      xb = *(const float4*)(xn + 4);
                xc_ = *(const float4*)(xn + 8); xd = *(const float4*)(xn + 12);
                wa = *(const uint4*)(wn);       wb = *(const uint4*)(wn + 8);
            }
            half8 af[2];
            af[0] = *(const half8*)(KA + (wave * 16 + lr) * 72 + lg * 8);
            af[1] = *(const half8*)(KA + (wave * 16 + lr) * 72 + 32 + lg * 8);
            __builtin_amdgcn_s_setprio(1);
            #pragma unroll
            for (int nt = 0; nt < 4; ++nt)
                #pragma unroll
                for (int s = 0; s < 2; ++s) {
                    const half8 bf = *(const half8*)(VA + (nt * 16 + lr) * 72 + s * 32 + lg * 8);
                    qacc[nt] = __builtin_amdgcn_mfma_f32_16x16x32_f16(af[s], bf, qacc[nt], 0, 0, 0);
                }
            __builtin_amdgcn_s_setprio(0);
        }
        #pragma unroll
        for (int nt = 0; nt < 4; ++nt) {
            const int d = nt * 16 + lr;
            const float bs = bq[h * 64 + d];
            #pragma unroll
            for (int r = 0; r < 4; ++r)
                QP[(wave * 16 + lg * 4 + r) * 72 + d] = (_Float16)((qacc[nt][r] + bs) * 0.125f);
        }
    }

    {
        const uchar4 mk = *(const uchar4*)(mask + b * 1024 + tid * 4);
        half4 mh = { mk.x ? (_Float16)0.f : (_Float16)1.f,
                     mk.y ? (_Float16)0.f : (_Float16)1.f,
                     mk.z ? (_Float16)0.f : (_Float16)1.f,
                     mk.w ? (_Float16)0.f : (_Float16)1.f };
        *(half4*)(Mh + tid * 4) = mh;
    }
    __syncthreads();

    half8 qf[2];
    if constexpr (QPRE) {
        const _Float16* qrp = Qp + (b * 1024 + q0 + wave * 16 + lr) * 768 + h * 64;
        qf[0] = *(const half8*)(qrp + lg * 8);
        qf[1] = *(const half8*)(qrp + 32 + lg * 8);
    } else {
        qf[0] = *(const half8*)(QP + (wave * 16 + lr) * 72 + lg * 8);
        qf[1] = *(const half8*)(QP + (wave * 16 + lr) * 72 + 32 + lg * 8);
    }

    f32x4 o[4] = {};
    float m_run = -1e30f, l_run = 0.f;
    const half2 one2 = { (_Float16)1.f, (_Float16)1.f };

    const _Float16* const Kg = K + (b * 1024 + pr) * 768 + h * 64 + pc;
    const _Float16* const Vg = Vt + (b * 768 + h * 64 + pr) * 1024 + pc;
    _Float16* const Pw = QP + wave * 1152;

    auto compute = [&](int kv0, const _Float16* Kb, const _Float16* Vb) {
        f32x4 st[4] = {};
        __builtin_amdgcn_s_setprio(1);
        #pragma unroll
        for (int t4 = 0; t4 < 4; ++t4)
            #pragma unroll
            for (int s = 0; s < 2; ++s) {
                const half8 a = *(const half8*)(Kb + (t4 * 16 + lr) * 72 + s * 32 + lg * 8);
                st[t4] = __builtin_amdgcn_mfma_f32_16x16x32_f16(a, qf[s], st[t4], 0, 0, 0);
            }
        __builtin_amdgcn_s_setprio(0);

        float mx = fmaxf(
            fmaxf(fmaxf(fmaxf(st[0][0], st[0][1]), fmaxf(st[0][2], st[0][3])),
                  fmaxf(fmaxf(st[1][0], st[1][1]), fmaxf(st[1][2], st[1][3]))),
            fmaxf(fmaxf(fmaxf(st[2][0], st[2][1]), fmaxf(st[2][2], st[2][3])),
                  fmaxf(fmaxf(st[3][0], st[3][1]), fmaxf(st[3][2], st[3][3]))));
        mx = fmaxf(mx, __shfl_xor(mx, 16));
        mx = fmaxf(mx, __shfl_xor(mx, 32));

        if (!__all(mx <= m_run + 8.f)) {
            const float m_new = fmaxf(m_run, mx);
            const float corr = __builtin_amdgcn_exp2f((m_run - m_new) * C2);
            l_run *= corr;
            #pragma unroll
            for (int i = 0; i < 4; ++i) o[i] *= corr;
            m_run = m_new;
        }
        const float nb = -m_run * C2;

        float ps = 0.f;
        #pragma unroll
        for (int t4 = 0; t4 < 4; ++t4) {
            half2 pa = cvt_pk(__builtin_amdgcn_exp2f(fmaf(st[t4][0], C2, nb)),
                              __builtin_amdgcn_exp2f(fmaf(st[t4][1], C2, nb)));
            half2 pb = cvt_pk(__builtin_amdgcn_exp2f(fmaf(st[t4][2], C2, nb)),
                              __builtin_amdgcn_exp2f(fmaf(st[t4][3], C2, nb)));
            const half4 mv = *(const half4*)(Mh + kv0 + t4 * 16 + lg * 4);
            const half2 mk0 = { mv[0], mv[1] };
            const half2 mk1 = { mv[2], mv[3] };
            pa *= mk0;
            pb *= mk1;
            ps = fdot2_acc(pa, one2, ps);
            ps = fdot2_acc(pb, one2, ps);
            union { half2 hh[2]; half4 v; } pk;
            pk.hh[0] = pa; pk.hh[1] = pb;
            *(half4*)(Pw + lr * 72 + t4 * 16 + lg * 4) = pk.v;
        }
        ps += __shfl_xor(ps, 16);
        ps += __shfl_xor(ps, 32);
        l_run += ps;

        asm volatile("s_waitcnt lgkmcnt(0)" ::: "memory");
        __builtin_amdgcn_sched_barrier(0);

        half8 pf[2];
        pf[0] = *(const half8*)(Pw + lr * 72 + lg * 8);
        pf[1] = *(const half8*)(Pw + lr * 72 + 32 + lg * 8);

        __builtin_amdgcn_s_setprio(1);
        #pragma unroll
        for (int dt = 0; dt < 4; ++dt)
            #pragma unroll
            for (int ks = 0; ks < 2; ++ks) {
                const half8 a = *(const half8*)(Vb + (dt * 16 + lr) * 72 + ks * 32 + lg * 8);
                o[dt] = __builtin_amdgcn_mfma_f32_16x16x32_f16(a, pf[ks], o[dt], 0, 0, 0);
            }
        __builtin_amdgcn_s_setprio(0);
    };

    uint4 ka0, ka1, va0, va1, kb0, kb1, vb0, vb1;
    ka0 = *(const uint4*)(Kg);            ka1 = *(const uint4*)(Kg + 8);
    va0 = *(const uint4*)(Vg);            va1 = *(const uint4*)(Vg + 8);
    kb0 = *(const uint4*)(Kg + 64 * 768); kb1 = *(const uint4*)(Kg + 64 * 768 + 8);
    vb0 = *(const uint4*)(Vg + 64);       vb1 = *(const uint4*)(Vg + 64 + 8);

    for (int j = 0; j < 8; ++j) {
        *(uint4*)(KA + pr * 72 + pc)     = ka0;
        *(uint4*)(KA + pr * 72 + pc + 8) = ka1;
        *(uint4*)(VA + pr * 72 + pc)     = va0;
        *(uint4*)(VA + pr * 72 + pc + 8) = va1;
        if (j < 7) {
            const int t = (2 * j + 2) * 64;
            ka0 = *(const uint4*)(Kg + t * 768);
            ka1 = *(const uint4*)(Kg + t * 768 + 8);
            va0 = *(const uint4*)(Vg + t);
            va1 = *(const uint4*)(Vg + t + 8);
        }
        __syncthreads();
        compute(2 * j * 64, KA, VA);

        *(uint4*)(KB + pr * 72 + pc)     = kb0;
        *(uint4*)(KB + pr * 72 + pc + 8) = kb1;
        *(uint4*)(VB + pr * 72 + pc)     = vb0;
        *(uint4*)(VB + pr * 72 + pc + 8) = vb1;
        if (j < 7) {
            const int t = (2 * j + 3) * 64;
            kb0 = *(const uint4*)(Kg + t * 768);
            kb1 = *(const uint4*)(Kg + t * 768 + 8);
            vb0 = *(const uint4*)(Vg + t);
            vb1 = *(const uint4*)(Vg + t + 8);
        }
        __syncthreads();
        compute((2 * j + 1) * 64, KB, VB);
    }

    const float inv = 1.f / l_run;
    const int qrow = b * 1024 + q0 + wave * 16 + lr;
    float* od = out + qrow * 768 + h * 64 + lg * 4;
    #pragma unroll
    for (int dt = 0; dt < 4; ++dt) {
        float4 v;
        v.x = o[dt][0] * inv; v.y = o[dt][1] * inv;
        v.z = o[dt][2] * inv; v.w = o[dt][3] * inv;
        *(float4*)(od + dt * 16) = v;
    }
}

extern "C" void kernel_launch(void* const* d_in, const int* in_sizes, int n_in,
                              void* d_out, int out_size, void* d_ws, size_t ws_size,
                              hipStream_t stream)
{
    const float* x  = (const float*)d_in[0];
    const float* y  = (const float*)d_in[1];
    const unsigned char* ym = (const unsigned char*)d_in[2];
    const float* Wq = (const float*)d_in[3];
    const float* bq = (const float*)d_in[4];
    const float* Wk = (const float*)d_in[5];
    const float* bk = (const float*)d_in[6];
    const float* Wv = (const float*)d_in[7];
    const float* bv = (const float*)d_in[8];

    _Float16* kws = (_Float16*)d_ws;             // [8192][768] K
    _Float16* vws = kws + 8192 * 768;            // [B][H*DV][L2] V^T
    _Float16* wt  = vws + 8192 * 768;            // [3][768][768] W^T (q,k,v)
    _Float16* qws = wt + 3 * 768 * 768;          // [8192][768] Q (optional)

    const size_t need = (size_t)(3 * 8192 * 768 + 3 * 768 * 768) * sizeof(_Float16);
    const bool qpre = ws_size >= need;

    wtrans_kernel<<<dim3(24, 24, 3), 256, 0, stream>>>(Wq, Wk, Wv, wt);
    projKV_kernel<<<dim3(64, 6, 2), 256, 0, stream>>>(y, wt, bk, bv, kws, vws);
    if (qpre) {
        projQ_kernel<<<dim3(64, 6), 256, 0, stream>>>(x, wt, bq, qws);
        attn_kernel<true><<<dim3(16, 12, 8), 256, 0, stream>>>(
            x, wt, bq, qws, kws, vws, ym, (float*)d_out);
    } else {
        attn_kernel<false><<<dim3(16, 12, 8), 256, 0, stream>>>(
            x, wt, bq, qws, kws, vws, ym, (float*)d_out);
    }
}

// Round 14
// 132.933 us; speedup vs baseline: 1.2425x; 1.0444x over previous
//
#include <hip/hip_runtime.h>

typedef _Float16 half8 __attribute__((ext_vector_type(8)));
typedef _Float16 half4 __attribute__((ext_vector_type(4)));
typedef _Float16 half2 __attribute__((ext_vector_type(2)));
typedef __fp16  fp16x2 __attribute__((ext_vector_type(2)));
typedef float f32x4 __attribute__((ext_vector_type(4)));

static __device__ __forceinline__ half2 cvt_pk(float a, float b) {
    fp16x2 r = __builtin_amdgcn_cvt_pkrtz(a, b);
    return __builtin_bit_cast(half2, r);
}
static __device__ __forceinline__ float fdot2_acc(half2 a, half2 b, float c) {
    return __builtin_amdgcn_fdot2(__builtin_bit_cast(fp16x2, a),
                                  __builtin_bit_cast(fp16x2, b), c, false);
}

// B=8, L1=L2=1024, D_IN=768, H=12, DK=DV=64, M=B*L=8192

// ---------------------------------------------------------------------------
// One-time W transpose+convert: Wt[z][n][k] fp16 = W_z[k][n] fp32, z in {q,k,v}
// ---------------------------------------------------------------------------
__global__ __launch_bounds__(256)
void wtrans_kernel(const float* __restrict__ Wq, const float* __restrict__ Wk,
                   const float* __restrict__ Wv, _Float16* __restrict__ Wt)
{
    __shared__ float t[32][33];
    const float* W = (blockIdx.z == 0) ? Wq : (blockIdx.z == 1) ? Wk : Wv;
    _Float16* dst = Wt + blockIdx.z * 768 * 768;
    const int tx = threadIdx.x & 31, ty = threadIdx.x >> 5;
    const int k0 = blockIdx.y * 32, n0 = blockIdx.x * 32;
    #pragma unroll
    for (int i = 0; i < 4; ++i)
        t[ty + 8 * i][tx] = W[(k0 + ty + 8 * i) * 768 + n0 + tx];
    __syncthreads();
    #pragma unroll
    for (int i = 0; i < 4; ++i)
        dst[(n0 + ty + 8 * i) * 768 + k0 + tx] = (_Float16)t[tx][ty + 8 * i];
}

// ---------------------------------------------------------------------------
// projKV (r9-verbatim structure, XCD-swizzled 1D grid of 768):
//   isv=0: K = y@Wk+bk -> [8192][768];  isv=1: V = y@Wv+bv -> Vt [B][H*DV][L2]
// ---------------------------------------------------------------------------
__global__ __launch_bounds__(256)
void projKV_kernel(const float* __restrict__ A, const _Float16* __restrict__ Wt,
                   const float* __restrict__ bk, const float* __restrict__ bv,
                   _Float16* __restrict__ kout, _Float16* __restrict__ vout)
{
    __shared__ __align__(16) char smem[34816];
    _Float16* const Alds = (_Float16*)smem;            // [128][40] padded
    _Float16* const Wlds = (_Float16*)smem + 128 * 40; // [128][40]
    _Float16* const Tlds = (_Float16*)smem;            // [128][136] epilogue

    const int tid  = threadIdx.x;
    const int lane = tid & 63;
    const int wave = tid >> 6;
    const int lr = lane & 15, lg = lane >> 4;
    const int wm = wave >> 1, wn = wave & 1;

    // XCD swizzle: 12 blocks sharing an A-panel stay on one XCD
    const int bid = blockIdx.x;                        // 0..767
    const int lid = (bid & 7) * 96 + (bid >> 3);
    const int m0  = (lid / 12) * 128;
    const int rem = lid % 12;
    const int n0  = (rem % 6) * 128;
    const int isv = rem / 6;

    const _Float16* __restrict__ W = Wt + (1 + isv) * 768 * 768;
    const float* __restrict__ bias = isv ? bv : bk;

    f32x4 acc[4][4] = {};

    const int ar   = tid >> 3;
    const int ac   = (tid & 7) * 4;
    const int wrow = tid >> 1;
    const int wcb  = (tid & 1) * 16;

    for (int kb = 0; kb < 24; ++kb) {
        #pragma unroll
        for (int i = 0; i < 4; ++i) {
            const int row = ar + 32 * i;
            const float4 v = *(const float4*)(A + (m0 + row) * 768 + kb * 32 + ac);
            half4 hh = { (_Float16)v.x, (_Float16)v.y, (_Float16)v.z, (_Float16)v.w };
            *(half4*)(Alds + row * 40 + ac) = hh;
        }
        {
            const _Float16* wtr = W + (n0 + wrow) * 768 + kb * 32 + wcb;
            *(uint4*)(Wlds + wrow * 40 + wcb)     = *(const uint4*)(wtr);
            *(uint4*)(Wlds + wrow * 40 + wcb + 8) = *(const uint4*)(wtr + 8);
        }
        __syncthreads();

        half8 af[4], bf[4];
        #pragma unroll
        for (int mt = 0; mt < 4; ++mt)
            af[mt] = *(const half8*)(Alds + (wm * 64 + mt * 16 + lr) * 40 + lg * 8);
        #pragma unroll
        for (int nt = 0; nt < 4; ++nt)
            bf[nt] = *(const half8*)(Wlds + (wn * 64 + nt * 16 + lr) * 40 + lg * 8);
        #pragma unroll
        for (int mt = 0; mt < 4; ++mt)
            #pragma unroll
            for (int nt = 0; nt < 4; ++nt)
                acc[mt][nt] = __builtin_amdgcn_mfma_f32_16x16x32_f16(af[mt], bf[nt], acc[mt][nt], 0, 0, 0);
        __syncthreads();
    }

    #pragma unroll
    for (int nt = 0; nt < 4; ++nt) {
        const int col = wn * 64 + nt * 16 + lr;
        const float bs = bias[n0 + col];
        #pragma unroll
        for (int mt = 0; mt < 4; ++mt) {
            #pragma unroll
            for (int r = 0; r < 4; ++r) {
                const int row = wm * 64 + mt * 16 + lg * 4 + r;
                const float val = acc[mt][nt][r] + bs;
                if (isv) Tlds[col * 136 + row] = (_Float16)val;
                else     Tlds[row * 136 + col] = (_Float16)val;
            }
        }
    }
    __syncthreads();

    const int crow = tid >> 1;
    const int cb   = (tid & 1) * 64;
    const _Float16* lsrc = Tlds + crow * 136 + cb;
    _Float16* gdst;
    if (isv) {
        const int bb  = m0 >> 10;
        const int l2b = m0 & 1023;
        gdst = vout + (bb * 768 + n0 + crow) * 1024 + l2b + cb;
    } else {
        gdst = kout + (m0 + crow) * 768 + n0 + cb;
    }
    #pragma unroll
    for (int it = 0; it < 8; ++it)
        *(uint4*)(gdst + it * 8) = *(const uint4*)(lsrc + it * 8);
}

// ---------------------------------------------------------------------------
// projQ (same structure, own dispatch, XCD-swizzled 1D grid of 384):
//   Q = (x@Wq+bq)*0.125 -> [8192][768]
// ---------------------------------------------------------------------------
__global__ __launch_bounds__(256)
void projQ_kernel(const float* __restrict__ x, const _Float16* __restrict__ Wt,
                  const float* __restrict__ bq, _Float16* __restrict__ qout)
{
    __shared__ __align__(16) char smem[34816];
    _Float16* const Alds = (_Float16*)smem;            // [128][40]
    _Float16* const Wlds = (_Float16*)smem + 128 * 40; // [128][40]
    _Float16* const Tlds = (_Float16*)smem;            // [128][136]

    const int tid  = threadIdx.x;
    const int lane = tid & 63;
    const int wave = tid >> 6;
    const int lr = lane & 15, lg = lane >> 4;
    const int wm = wave >> 1, wn = wave & 1;

    const int bid = blockIdx.x;                        // 0..383
    const int lid = (bid & 7) * 48 + (bid >> 3);
    const int m0  = (lid / 6) * 128;
    const int n0  = (lid % 6) * 128;

    const _Float16* __restrict__ W = Wt;               // q slice

    f32x4 acc[4][4] = {};

    const int ar   = tid >> 3;
    const int ac   = (tid & 7) * 4;
    const int wrow = tid >> 1;
    const int wcb  = (tid & 1) * 16;

    for (int kb = 0; kb < 24; ++kb) {
        #pragma unroll
        for (int i = 0; i < 4; ++i) {
            const int row = ar + 32 * i;
            const float4 v = *(const float4*)(x + (m0 + row) * 768 + kb * 32 + ac);
            half4 hh = { (_Float16)v.x, (_Float16)v.y, (_Float16)v.z, (_Float16)v.w };
            *(half4*)(Alds + row * 40 + ac) = hh;
        }
        {
            const _Float16* wtr = W + (n0 + wrow) * 768 + kb * 32 + wcb;
            *(uint4*)(Wlds + wrow * 40 + wcb)     = *(const uint4*)(wtr);
            *(uint4*)(Wlds + wrow * 40 + wcb + 8) = *(const uint4*)(wtr + 8);
        }
        __syncthreads();

        half8 af[4], bf[4];
        #pragma unroll
        for (int mt = 0; mt < 4; ++mt)
            af[mt] = *(const half8*)(Alds + (wm * 64 + mt * 16 + lr) * 40 + lg * 8);
        #pragma unroll
        for (int nt = 0; nt < 4; ++nt)
            bf[nt] = *(const half8*)(Wlds + (wn * 64 + nt * 16 + lr) * 40 + lg * 8);
        #pragma unroll
        for (int mt = 0; mt < 4; ++mt)
            #pragma unroll
            for (int nt = 0; nt < 4; ++nt)
                acc[mt][nt] = __builtin_amdgcn_mfma_f32_16x16x32_f16(af[mt], bf[nt], acc[mt][nt], 0, 0, 0);
        __syncthreads();
    }

    #pragma unroll
    for (int nt = 0; nt < 4; ++nt) {
        const int col = wn * 64 + nt * 16 + lr;
        const float bs = bq[n0 + col];
        #pragma unroll
        for (int mt = 0; mt < 4; ++mt) {
            #pragma unroll
            for (int r = 0; r < 4; ++r) {
                const int row = wm * 64 + mt * 16 + lg * 4 + r;
                Tlds[row * 136 + col] = (_Float16)((acc[mt][nt][r] + bs) * 0.125f);
            }
        }
    }
    __syncthreads();

    const int crow = tid >> 1;
    const int cb   = (tid & 1) * 64;
    const _Float16* lsrc = Tlds + crow * 136 + cb;
    _Float16* gdst = qout + (m0 + crow) * 768 + n0 + cb;
    #pragma unroll
    for (int it = 0; it < 8; ++it)
        *(uint4*)(gdst + it * 8) = *(const uint4*)(lsrc + it * 8);
}

// ---------------------------------------------------------------------------
// Fused attention, per block (q-tile=128, h, b); 512 threads / 8 waves.
// XCD-swizzled 1D grid of 768 (each XCD owns one batch -> K/V L2-resident).
// QPRE=1: Q precomputed. Phase 2: flash loop, KVBLK=64, double-buffered LDS
// (1 barrier/tile), 2-tile register prefetch, exp2 softmax, defer-max.
// ---------------------------------------------------------------------------
template<bool QPRE>
__global__ __launch_bounds__(512)
void attn_kernel(const float* __restrict__ x, const _Float16* __restrict__ Wtq,
                 const float* __restrict__ bq, const _Float16* __restrict__ Qp,
                 const _Float16* __restrict__ K, const _Float16* __restrict__ Vt,
                 const unsigned char* __restrict__ mask,
                 float* __restrict__ out)
{
    __shared__ __align__(16) char smem[57344];
    _Float16* const KA = (_Float16*)smem;              // K buf A [64][72]
    _Float16* const KB = (_Float16*)(smem + 9216);     // K buf B
    _Float16* const VA = (_Float16*)(smem + 18432);    // V buf A
    _Float16* const VB = (_Float16*)(smem + 27648);    // V buf B
    _Float16* const QP = (_Float16*)(smem + 36864);    // [128][72]: Q / per-wave P
    _Float16* const Mh = (_Float16*)(smem + 55296);    // [1024] fp16 0/1

    const int tid  = threadIdx.x;
    const int lane = tid & 63;
    const int wave = tid >> 6;                         // 0..7
    const int lr = lane & 15, lg = lane >> 4;

    const int bid = blockIdx.x;                        // 0..767
    const int lid = (bid & 7) * 96 + (bid >> 3);       // XCD swizzle
    const int q0 = (lid & 7) * 128;
    const int h  = (lid >> 3) % 12;
    const int b  = lid / 96;

    const float C2 = 1.44269504f;       // log2(e)

    if constexpr (!QPRE) {
        // ---- fallback phase 1: Q[128][64] = x-tile @ Wtq-slice, BK=64 ----
        _Float16* const Xl = KA;                       // [128][72] (KA+KB contig)
        const int xr = tid >> 2, xc = (tid & 3) * 16;  // x: 128 rows x 64 f32
        const int wr = tid >> 3, wc = (tid & 7) * 8;   // W: 64 n x 64 k halves
        f32x4 qacc[4] = {};
        for (int kb = 0; kb < 12; ++kb) {
            const float* xrow = x + (b * 1024 + q0 + xr) * 768 + kb * 64 + xc;
            const float4 v0 = *(const float4*)(xrow);
            const float4 v1 = *(const float4*)(xrow + 4);
            const float4 v2 = *(const float4*)(xrow + 8);
            const float4 v3 = *(const float4*)(xrow + 12);
            const uint4 wv = *(const uint4*)(Wtq + (h * 64 + wr) * 768 + kb * 64 + wc);
            union { half2 hh[4]; half8 v; } u0, u1;
            u0.hh[0] = cvt_pk(v0.x, v0.y); u0.hh[1] = cvt_pk(v0.z, v0.w);
            u0.hh[2] = cvt_pk(v1.x, v1.y); u0.hh[3] = cvt_pk(v1.z, v1.w);
            u1.hh[0] = cvt_pk(v2.x, v2.y); u1.hh[1] = cvt_pk(v2.z, v2.w);
            u1.hh[2] = cvt_pk(v3.x, v3.y); u1.hh[3] = cvt_pk(v3.z, v3.w);
            *(half8*)(Xl + xr * 72 + xc)     = u0.v;
            *(half8*)(Xl + xr * 72 + xc + 8) = u1.v;
            *(uint4*)(VA + wr * 72 + wc)     = wv;
            __syncthreads();
            half8 af[2];
            af[0] = *(const half8*)(Xl + (wave * 16 + lr) * 72 + lg * 8);
            af[1] = *(const half8*)(Xl + (wave * 16 + lr) * 72 + 32 + lg * 8);
            #pragma unroll
            for (int nt = 0; nt < 4; ++nt)
                #pragma unroll
                for (int s = 0; s < 2; ++s) {
                    const half8 bf = *(const half8*)(VA + (nt * 16 + lr) * 72 + s * 32 + lg * 8);
                    qacc[nt] = __builtin_amdgcn_mfma_f32_16x16x32_f16(af[s], bf, qacc[nt], 0, 0, 0);
                }
            __syncthreads();
        }
        #pragma unroll
        for (int nt = 0; nt < 4; ++nt) {
            const int d = nt * 16 + lr;
            const float bs = bq[h * 64 + d];
            #pragma unroll
            for (int r = 0; r < 4; ++r)
                QP[(wave * 16 + lg * 4 + r) * 72 + d] = (_Float16)((qacc[nt][r] + bs) * 0.125f);
        }
    }

    // fp16 multiplicative mask (1 = keep, 0 = masked), 2 entries/thread
    {
        const uchar2 mk = *(const uchar2*)(mask + b * 1024 + tid * 2);
        Mh[tid * 2]     = mk.x ? (_Float16)0.f : (_Float16)1.f;
        Mh[tid * 2 + 1] = mk.y ? (_Float16)0.f : (_Float16)1.f;
    }
    __syncthreads();

    // Q fragment (B-operand of S^T): lane holds Q[q=lr][d=32s+8lg+j], pre-scaled
    half8 qf[2];
    if constexpr (QPRE) {
        const _Float16* qrp = Qp + (b * 1024 + q0 + wave * 16 + lr) * 768 + h * 64;
        qf[0] = *(const half8*)(qrp + lg * 8);
        qf[1] = *(const half8*)(qrp + 32 + lg * 8);
    } else {
        qf[0] = *(const half8*)(QP + (wave * 16 + lr) * 72 + lg * 8);
        qf[1] = *(const half8*)(QP + (wave * 16 + lr) * 72 + 32 + lg * 8);
        __syncthreads();   // QP becomes the P buffer below
    }

    f32x4 o[4] = {};
    float m_run = -1e30f, l_run = 0.f;
    const half2 one2 = { (_Float16)1.f, (_Float16)1.f };

    const int sr  = tid >> 3;            // 0..63 staging row
    const int sc8 = (tid & 7) * 8;       // staging col (8 halves)
    const _Float16* const Kg = K + (b * 1024 + sr) * 768 + h * 64 + sc8;
    const _Float16* const Vg = Vt + (b * 768 + h * 64 + sr) * 1024 + sc8;
    _Float16* const Pw = QP + wave * 1152;

    auto compute = [&](int kv0, const _Float16* Kb, const _Float16* Vb) {
        f32x4 st[4] = {};
        __builtin_amdgcn_s_setprio(1);
        #pragma unroll
        for (int t4 = 0; t4 < 4; ++t4)
            #pragma unroll
            for (int s = 0; s < 2; ++s) {
                const half8 a = *(const half8*)(Kb + (t4 * 16 + lr) * 72 + s * 32 + lg * 8);
                st[t4] = __builtin_amdgcn_mfma_f32_16x16x32_f16(a, qf[s], st[t4], 0, 0, 0);
            }
        __builtin_amdgcn_s_setprio(0);

        float mx = fmaxf(
            fmaxf(fmaxf(fmaxf(st[0][0], st[0][1]), fmaxf(st[0][2], st[0][3])),
                  fmaxf(fmaxf(st[1][0], st[1][1]), fmaxf(st[1][2], st[1][3]))),
            fmaxf(fmaxf(fmaxf(st[2][0], st[2][1]), fmaxf(st[2][2], st[2][3])),
                  fmaxf(fmaxf(st[3][0], st[3][1]), fmaxf(st[3][2], st[3][3]))));
        mx = fmaxf(mx, __shfl_xor(mx, 16));
        mx = fmaxf(mx, __shfl_xor(mx, 32));

        if (!__all(mx <= m_run + 8.f)) {
            const float m_new = fmaxf(m_run, mx);
            const float corr = __builtin_amdgcn_exp2f((m_run - m_new) * C2);
            l_run *= corr;
            #pragma unroll
            for (int i = 0; i < 4; ++i) o[i] *= corr;
            m_run = m_new;
        }
        const float nb = -m_run * C2;

        float ps = 0.f;
        #pragma unroll
        for (int t4 = 0; t4 < 4; ++t4) {
            half2 pa = cvt_pk(__builtin_amdgcn_exp2f(fmaf(st[t4][0], C2, nb)),
                              __builtin_amdgcn_exp2f(fmaf(st[t4][1], C2, nb)));
            half2 pb = cvt_pk(__builtin_amdgcn_exp2f(fmaf(st[t4][2], C2, nb)),
                              __builtin_amdgcn_exp2f(fmaf(st[t4][3], C2, nb)));
            const half4 mv = *(const half4*)(Mh + kv0 + t4 * 16 + lg * 4);
            const half2 mk0 = { mv[0], mv[1] };
            const half2 mk1 = { mv[2], mv[3] };
            pa *= mk0;
            pb *= mk1;
            ps = fdot2_acc(pa, one2, ps);
            ps = fdot2_acc(pb, one2, ps);
            union { half2 hh[2]; half4 v; } pk;
            pk.hh[0] = pa; pk.hh[1] = pb;
            *(half4*)(Pw + lr * 72 + t4 * 16 + lg * 4) = pk.v;
        }
        ps += __shfl_xor(ps, 16);
        ps += __shfl_xor(ps, 32);
        l_run += ps;

        asm volatile("s_waitcnt lgkmcnt(0)" ::: "memory");
        __builtin_amdgcn_sched_barrier(0);

        half8 pf[2];
        pf[0] = *(const half8*)(Pw + lr * 72 + lg * 8);
        pf[1] = *(const half8*)(Pw + lr * 72 + 32 + lg * 8);

        __builtin_amdgcn_s_setprio(1);
        #pragma unroll
        for (int dt = 0; dt < 4; ++dt)
            #pragma unroll
            for (int ks = 0; ks < 2; ++ks) {
                const half8 a = *(const half8*)(Vb + (dt * 16 + lr) * 72 + ks * 32 + lg * 8);
                o[dt] = __builtin_amdgcn_mfma_f32_16x16x32_f16(a, pf[ks], o[dt], 0, 0, 0);
            }
        __builtin_amdgcn_s_setprio(0);
    };

    // 2-deep register prefetch: tiles 0,1 before the loop (1 uint4 per buffer)
    uint4 ka, va, kb2, vb2;
    ka  = *(const uint4*)(Kg);
    va  = *(const uint4*)(Vg);
    kb2 = *(const uint4*)(Kg + 64 * 768);
    vb2 = *(const uint4*)(Vg + 64);

    for (int j = 0; j < 8; ++j) {
        // ---- step 2j (buf A) ----
        *(uint4*)(KA + sr * 72 + sc8) = ka;
        *(uint4*)(VA + sr * 72 + sc8) = va;
        if (j < 7) {
            const int t = (2 * j + 2) * 64;
            ka = *(const uint4*)(Kg + t * 768);
            va = *(const uint4*)(Vg + t);
        }
        __syncthreads();
        compute(2 * j * 64, KA, VA);

        // ---- step 2j+1 (buf B) ----
        *(uint4*)(KB + sr * 72 + sc8) = kb2;
        *(uint4*)(VB + sr * 72 + sc8) = vb2;
        if (j < 7) {
            const int t = (2 * j + 3) * 64;
            kb2 = *(const uint4*)(Kg + t * 768);
            vb2 = *(const uint4*)(Vg + t);
        }
        __syncthreads();
        compute((2 * j + 1) * 64, KB, VB);
    }

    const float inv = 1.f / l_run;
    const int qrow = b * 1024 + q0 + wave * 16 + lr;
    float* od = out + qrow * 768 + h * 64 + lg * 4;
    #pragma unroll
    for (int dt = 0; dt < 4; ++dt) {
        float4 v;
        v.x = o[dt][0] * inv; v.y = o[dt][1] * inv;
        v.z = o[dt][2] * inv; v.w = o[dt][3] * inv;
        *(float4*)(od + dt * 16) = v;
    }
}

extern "C" void kernel_launch(void* const* d_in, const int* in_sizes, int n_in,
                              void* d_out, int out_size, void* d_ws, size_t ws_size,
                              hipStream_t stream)
{
    const float* x  = (const float*)d_in[0];
    const float* y  = (const float*)d_in[1];
    const unsigned char* ym = (const unsigned char*)d_in[2];
    const float* Wq = (const float*)d_in[3];
    const float* bq = (const float*)d_in[4];
    const float* Wk = (const float*)d_in[5];
    const float* bk = (const float*)d_in[6];
    const float* Wv = (const float*)d_in[7];
    const float* bv = (const float*)d_in[8];

    _Float16* kws = (_Float16*)d_ws;             // [8192][768] K
    _Float16* vws = kws + 8192 * 768;            // [B][H*DV][L2] V^T
    _Float16* wt  = vws + 8192 * 768;            // [3][768][768] W^T (q,k,v)
    _Float16* qws = wt + 3 * 768 * 768;          // [8192][768] Q (optional)

    const size_t need = (size_t)(3 * 8192 * 768 + 3 * 768 * 768) * sizeof(_Float16);
    const bool qpre = ws_size >= need;

    wtrans_kernel<<<dim3(24, 24, 3), 256, 0, stream>>>(Wq, Wk, Wv, wt);
    projKV_kernel<<<768, 256, 0, stream>>>(y, wt, bk, bv, kws, vws);
    if (qpre) {
        projQ_kernel<<<384, 256, 0, stream>>>(x, wt, bq, qws);
        attn_kernel<true><<<768, 512, 0, stream>>>(
            x, wt, bq, qws, kws, vws, ym, (float*)d_out);
    } else {
        attn_kernel<false><<<768, 512, 0, stream>>>(
            x, wt, bq, qws, kws, vws, ym, (float*)d_out);
    }
}

// Round 15
// 131.646 us; speedup vs baseline: 1.2546x; 1.0098x over previous
//
#include <hip/hip_runtime.h>

typedef _Float16 half8 __attribute__((ext_vector_type(8)));
typedef _Float16 half4 __attribute__((ext_vector_type(4)));
typedef _Float16 half2 __attribute__((ext_vector_type(2)));
typedef __fp16  fp16x2 __attribute__((ext_vector_type(2)));
typedef float f32x4 __attribute__((ext_vector_type(4)));
typedef float f32x16 __attribute__((ext_vector_type(16)));

static __device__ __forceinline__ half2 cvt_pk(float a, float b) {
    fp16x2 r = __builtin_amdgcn_cvt_pkrtz(a, b);
    return __builtin_bit_cast(half2, r);
}
static __device__ __forceinline__ float fdot2_acc(half2 a, half2 b, float c) {
    return __builtin_amdgcn_fdot2(__builtin_bit_cast(fp16x2, a),
                                  __builtin_bit_cast(fp16x2, b), c, false);
}

// B=8, L1=L2=1024, D_IN=768, H=12, DK=DV=64, M=B*L=8192

// ---------------------------------------------------------------------------
// One-time W transpose+convert: Wt[z][n][k] fp16 = W_z[k][n] fp32, z in {q,k,v}
// ---------------------------------------------------------------------------
__global__ __launch_bounds__(256)
void wtrans_kernel(const float* __restrict__ Wq, const float* __restrict__ Wk,
                   const float* __restrict__ Wv, _Float16* __restrict__ Wt)
{
    __shared__ float t[32][33];
    const float* W = (blockIdx.z == 0) ? Wq : (blockIdx.z == 1) ? Wk : Wv;
    _Float16* dst = Wt + blockIdx.z * 768 * 768;
    const int tx = threadIdx.x & 31, ty = threadIdx.x >> 5;
    const int k0 = blockIdx.y * 32, n0 = blockIdx.x * 32;
    #pragma unroll
    for (int i = 0; i < 4; ++i)
        t[ty + 8 * i][tx] = W[(k0 + ty + 8 * i) * 768 + n0 + tx];
    __syncthreads();
    #pragma unroll
    for (int i = 0; i < 4; ++i)
        dst[(n0 + ty + 8 * i) * 768 + k0 + tx] = (_Float16)t[tx][ty + 8 * i];
}

// ---------------------------------------------------------------------------
// projKV (XCD-swizzled): isv=0: K = y@Wk+bk; isv=1: V = y@Wv+bv -> Vt
// ---------------------------------------------------------------------------
__global__ __launch_bounds__(256)
void projKV_kernel(const float* __restrict__ A, const _Float16* __restrict__ Wt,
                   const float* __restrict__ bk, const float* __restrict__ bv,
                   _Float16* __restrict__ kout, _Float16* __restrict__ vout)
{
    __shared__ __align__(16) char smem[34816];
    _Float16* const Alds = (_Float16*)smem;            // [128][40] padded
    _Float16* const Wlds = (_Float16*)smem + 128 * 40; // [128][40]
    _Float16* const Tlds = (_Float16*)smem;            // [128][136] epilogue

    const int tid  = threadIdx.x;
    const int lane = tid & 63;
    const int wave = tid >> 6;
    const int lr = lane & 15, lg = lane >> 4;
    const int wm = wave >> 1, wn = wave & 1;

    const int bid = blockIdx.x;                        // 0..767
    const int lid = (bid & 7) * 96 + (bid >> 3);
    const int m0  = (lid / 12) * 128;
    const int rem = lid % 12;
    const int n0  = (rem % 6) * 128;
    const int isv = rem / 6;

    const _Float16* __restrict__ W = Wt + (1 + isv) * 768 * 768;
    const float* __restrict__ bias = isv ? bv : bk;

    f32x4 acc[4][4] = {};

    const int ar   = tid >> 3;
    const int ac   = (tid & 7) * 4;
    const int wrow = tid >> 1;
    const int wcb  = (tid & 1) * 16;

    for (int kb = 0; kb < 24; ++kb) {
        #pragma unroll
        for (int i = 0; i < 4; ++i) {
            const int row = ar + 32 * i;
            const float4 v = *(const float4*)(A + (m0 + row) * 768 + kb * 32 + ac);
            half4 hh = { (_Float16)v.x, (_Float16)v.y, (_Float16)v.z, (_Float16)v.w };
            *(half4*)(Alds + row * 40 + ac) = hh;
        }
        {
            const _Float16* wtr = W + (n0 + wrow) * 768 + kb * 32 + wcb;
            *(uint4*)(Wlds + wrow * 40 + wcb)     = *(const uint4*)(wtr);
            *(uint4*)(Wlds + wrow * 40 + wcb + 8) = *(const uint4*)(wtr + 8);
        }
        __syncthreads();

        half8 af[4], bf[4];
        #pragma unroll
        for (int mt = 0; mt < 4; ++mt)
            af[mt] = *(const half8*)(Alds + (wm * 64 + mt * 16 + lr) * 40 + lg * 8);
        #pragma unroll
        for (int nt = 0; nt < 4; ++nt)
            bf[nt] = *(const half8*)(Wlds + (wn * 64 + nt * 16 + lr) * 40 + lg * 8);
        #pragma unroll
        for (int mt = 0; mt < 4; ++mt)
            #pragma unroll
            for (int nt = 0; nt < 4; ++nt)
                acc[mt][nt] = __builtin_amdgcn_mfma_f32_16x16x32_f16(af[mt], bf[nt], acc[mt][nt], 0, 0, 0);
        __syncthreads();
    }

    #pragma unroll
    for (int nt = 0; nt < 4; ++nt) {
        const int col = wn * 64 + nt * 16 + lr;
        const float bs = bias[n0 + col];
        #pragma unroll
        for (int mt = 0; mt < 4; ++mt) {
            #pragma unroll
            for (int r = 0; r < 4; ++r) {
                const int row = wm * 64 + mt * 16 + lg * 4 + r;
                const float val = acc[mt][nt][r] + bs;
                if (isv) Tlds[col * 136 + row] = (_Float16)val;
                else     Tlds[row * 136 + col] = (_Float16)val;
            }
        }
    }
    __syncthreads();

    const int crow = tid >> 1;
    const int cb   = (tid & 1) * 64;
    const _Float16* lsrc = Tlds + crow * 136 + cb;
    _Float16* gdst;
    if (isv) {
        const int bb  = m0 >> 10;
        const int l2b = m0 & 1023;
        gdst = vout + (bb * 768 + n0 + crow) * 1024 + l2b + cb;
    } else {
        gdst = kout + (m0 + crow) * 768 + n0 + cb;
    }
    #pragma unroll
    for (int it = 0; it < 8; ++it)
        *(uint4*)(gdst + it * 8) = *(const uint4*)(lsrc + it * 8);
}

// ---------------------------------------------------------------------------
// projQ (XCD-swizzled): Q = (x@Wq+bq)*0.125 -> [8192][768]
// ---------------------------------------------------------------------------
__global__ __launch_bounds__(256)
void projQ_kernel(const float* __restrict__ x, const _Float16* __restrict__ Wt,
                  const float* __restrict__ bq, _Float16* __restrict__ qout)
{
    __shared__ __align__(16) char smem[34816];
    _Float16* const Alds = (_Float16*)smem;            // [128][40]
    _Float16* const Wlds = (_Float16*)smem + 128 * 40; // [128][40]
    _Float16* const Tlds = (_Float16*)smem;            // [128][136]

    const int tid  = threadIdx.x;
    const int lane = tid & 63;
    const int wave = tid >> 6;
    const int lr = lane & 15, lg = lane >> 4;
    const int wm = wave >> 1, wn = wave & 1;

    const int bid = blockIdx.x;                        // 0..383
    const int lid = (bid & 7) * 48 + (bid >> 3);
    const int m0  = (lid / 6) * 128;
    const int n0  = (lid % 6) * 128;

    const _Float16* __restrict__ W = Wt;               // q slice

    f32x4 acc[4][4] = {};

    const int ar   = tid >> 3;
    const int ac   = (tid & 7) * 4;
    const int wrow = tid >> 1;
    const int wcb  = (tid & 1) * 16;

    for (int kb = 0; kb < 24; ++kb) {
        #pragma unroll
        for (int i = 0; i < 4; ++i) {
            const int row = ar + 32 * i;
            const float4 v = *(const float4*)(x + (m0 + row) * 768 + kb * 32 + ac);
            half4 hh = { (_Float16)v.x, (_Float16)v.y, (_Float16)v.z, (_Float16)v.w };
            *(half4*)(Alds + row * 40 + ac) = hh;
        }
        {
            const _Float16* wtr = W + (n0 + wrow) * 768 + kb * 32 + wcb;
            *(uint4*)(Wlds + wrow * 40 + wcb)     = *(const uint4*)(wtr);
            *(uint4*)(Wlds + wrow * 40 + wcb + 8) = *(const uint4*)(wtr + 8);
        }
        __syncthreads();

        half8 af[4], bf[4];
        #pragma unroll
        for (int mt = 0; mt < 4; ++mt)
            af[mt] = *(const half8*)(Alds + (wm * 64 + mt * 16 + lr) * 40 + lg * 8);
        #pragma unroll
        for (int nt = 0; nt < 4; ++nt)
            bf[nt] = *(const half8*)(Wlds + (wn * 64 + nt * 16 + lr) * 40 + lg * 8);
        #pragma unroll
        for (int mt = 0; mt < 4; ++mt)
            #pragma unroll
            for (int nt = 0; nt < 4; ++nt)
                acc[mt][nt] = __builtin_amdgcn_mfma_f32_16x16x32_f16(af[mt], bf[nt], acc[mt][nt], 0, 0, 0);
        __syncthreads();
    }

    #pragma unroll
    for (int nt = 0; nt < 4; ++nt) {
        const int col = wn * 64 + nt * 16 + lr;
        const float bs = bq[n0 + col];
        #pragma unroll
        for (int mt = 0; mt < 4; ++mt) {
            #pragma unroll
            for (int r = 0; r < 4; ++r) {
                const int row = wm * 64 + mt * 16 + lg * 4 + r;
                Tlds[row * 136 + col] = (_Float16)((acc[mt][nt][r] + bs) * 0.125f);
            }
        }
    }
    __syncthreads();

    const int crow = tid >> 1;
    const int cb   = (tid & 1) * 64;
    const _Float16* lsrc = Tlds + crow * 136 + cb;
    _Float16* gdst = qout + (m0 + crow) * 768 + n0 + cb;
    #pragma unroll
    for (int it = 0; it < 8; ++it)
        *(uint4*)(gdst + it * 8) = *(const uint4*)(lsrc + it * 8);
}

// ---------------------------------------------------------------------------
// Fused attention, 32x32 MFMA. Block = (q-tile 128, h, b), 256 thr / 4 waves,
// each wave owns 32 q-rows. XCD-swizzled grid of 768. KVBLK=64, double-buffered
// LDS (1 barrier/tile), 1-tile register prefetch, in-register P via
// shfl_xor(32) quad exchange, exp2 softmax, defer-max.
// S^T layout (mfma(K,Q)): col q = lane&31, row kv = (r&3)+8(r>>2)+4hi (+32*t).
// ---------------------------------------------------------------------------
template<bool QPRE>
__global__ __launch_bounds__(256)
void attn_kernel(const float* __restrict__ x, const _Float16* __restrict__ Wtq,
                 const float* __restrict__ bq, const _Float16* __restrict__ Qp,
                 const _Float16* __restrict__ K, const _Float16* __restrict__ Vt,
                 const unsigned char* __restrict__ mask,
                 float* __restrict__ out)
{
    __shared__ __align__(16) char smem[QPRE ? 38912 : 57344];
    _Float16* const KA = (_Float16*)smem;              // K buf A [64][72]
    _Float16* const KB = (_Float16*)(smem + 9216);     // K buf B
    _Float16* const VA = (_Float16*)(smem + 18432);    // V buf A
    _Float16* const VB = (_Float16*)(smem + 27648);    // V buf B
    _Float16* const Mh = (_Float16*)(smem + 36864);    // [1024] fp16 0/1

    const int tid  = threadIdx.x;
    const int lane = tid & 63;
    const int wave = tid >> 6;                         // 0..3
    const int l31  = lane & 31;
    const int hi   = lane >> 5;

    const int bid = blockIdx.x;                        // 0..767
    const int lid = (bid & 7) * 96 + (bid >> 3);       // XCD swizzle
    const int q0 = (lid & 7) * 128;
    const int h  = (lid >> 3) % 12;
    const int b  = lid / 96;

    const float C2 = 1.44269504f;       // log2(e)

    if constexpr (!QPRE) {
        // ---- fallback: Q[128][64] = (x@Wq+bq)/8 via 16x16 MFMA, BK=32 ----
        _Float16* const Xl  = (_Float16*)smem;             // [128][72]
        _Float16* const Wl  = (_Float16*)(smem + 18432);   // [64][72]
        _Float16* const QPl = (_Float16*)(smem + 38912);   // [128][72]
        const int lr = lane & 15, lg = lane >> 4;
        const int xr = tid >> 1, xc = (tid & 1) * 16;
        const int wr = tid >> 2, wc = (tid & 3) * 8;
        f32x4 qacc[2][4] = {};
        for (int kb = 0; kb < 24; ++kb) {
            const float* xrow = x + (b * 1024 + q0 + xr) * 768 + kb * 32 + xc;
            const float4 v0 = *(const float4*)(xrow);
            const float4 v1 = *(const float4*)(xrow + 4);
            const float4 v2 = *(const float4*)(xrow + 8);
            const float4 v3 = *(const float4*)(xrow + 12);
            const uint4 wv = *(const uint4*)(Wtq + (h * 64 + wr) * 768 + kb * 32 + wc);
            union { half2 hh[4]; half8 v; } u0, u1;
            u0.hh[0] = cvt_pk(v0.x, v0.y); u0.hh[1] = cvt_pk(v0.z, v0.w);
            u0.hh[2] = cvt_pk(v1.x, v1.y); u0.hh[3] = cvt_pk(v1.z, v1.w);
            u1.hh[0] = cvt_pk(v2.x, v2.y); u1.hh[1] = cvt_pk(v2.z, v2.w);
            u1.hh[2] = cvt_pk(v3.x, v3.y); u1.hh[3] = cvt_pk(v3.z, v3.w);
            *(half8*)(Xl + xr * 72 + xc)     = u0.v;
            *(half8*)(Xl + xr * 72 + xc + 8) = u1.v;
            *(uint4*)(Wl + wr * 72 + wc)     = wv;
            __syncthreads();
            #pragma unroll
            for (int c = 0; c < 2; ++c) {
                const half8 af = *(const half8*)(Xl + (c * 64 + wave * 16 + lr) * 72 + lg * 8);
                #pragma unroll
                for (int nt = 0; nt < 4; ++nt) {
                    const half8 bf = *(const half8*)(Wl + (nt * 16 + lr) * 72 + lg * 8);
                    qacc[c][nt] = __builtin_amdgcn_mfma_f32_16x16x32_f16(af, bf, qacc[c][nt], 0, 0, 0);
                }
            }
            __syncthreads();
        }
        #pragma unroll
        for (int c = 0; c < 2; ++c)
            #pragma unroll
            for (int nt = 0; nt < 4; ++nt) {
                const int d = nt * 16 + lr;
                const float bs = bq[h * 64 + d];
                #pragma unroll
                for (int r = 0; r < 4; ++r)
                    QPl[(c * 64 + wave * 16 + lg * 4 + r) * 72 + d] =
                        (_Float16)((qacc[c][nt][r] + bs) * 0.125f);
            }
        __syncthreads();
    }

    // fp16 multiplicative mask (1 = keep, 0 = masked)
    {
        const uchar4 mk = *(const uchar4*)(mask + b * 1024 + tid * 4);
        half4 mh = { mk.x ? (_Float16)0.f : (_Float16)1.f,
                     mk.y ? (_Float16)0.f : (_Float16)1.f,
                     mk.z ? (_Float16)0.f : (_Float16)1.f,
                     mk.w ? (_Float16)0.f : (_Float16)1.f };
        *(half4*)(Mh + tid * 4) = mh;
    }

    // Q B-fragments (32x32x16): lane holds Q[q = q0 + wave*32 + l31]
    //                                      [d = ks*16 + hi*8 + j], pre-scaled.
    half8 qf[4];
    if constexpr (QPRE) {
        const _Float16* qrp = Qp + (b * 1024 + q0 + wave * 32 + l31) * 768 + h * 64;
        #pragma unroll
        for (int ks = 0; ks < 4; ++ks)
            qf[ks] = *(const half8*)(qrp + ks * 16 + hi * 8);
    } else {
        _Float16* const QPl = (_Float16*)(smem + 38912);
        #pragma unroll
        for (int ks = 0; ks < 4; ++ks)
            qf[ks] = *(const half8*)(QPl + (wave * 32 + l31) * 72 + ks * 16 + hi * 8);
    }

    f32x16 o[2] = {};
    float m_run = -1e30f, l_run = 0.f;
    const half2 one2 = { (_Float16)1.f, (_Float16)1.f };

    const int sr  = tid >> 2;            // 0..63 staging row
    const int sc  = (tid & 3) * 16;      // staging col (16 halves)
    const _Float16* const Kg = K + (b * 1024 + sr) * 768 + h * 64 + sc;
    const _Float16* const Vg = Vt + (b * 768 + h * 64 + sr) * 1024 + sc;

    auto compute = [&](int kv0, const _Float16* Kb, const _Float16* Vb) {
        // S^T: 2 kv-subtiles of 32 x (q 32), K=16 x4 steps
        f32x16 st[2] = {};
        __builtin_amdgcn_s_setprio(1);
        #pragma unroll
        for (int ks = 0; ks < 4; ++ks) {
            const half8 a0 = *(const half8*)(Kb + l31 * 72 + ks * 16 + hi * 8);
            const half8 a1 = *(const half8*)(Kb + (l31 + 32) * 72 + ks * 16 + hi * 8);
            st[0] = __builtin_amdgcn_mfma_f32_32x32x16_f16(a0, qf[ks], st[0], 0, 0, 0);
            st[1] = __builtin_amdgcn_mfma_f32_32x32x16_f16(a1, qf[ks], st[1], 0, 0, 0);
        }
        __builtin_amdgcn_s_setprio(0);

        // row max over this lane's 32 kv values, then partner (q-sharing) lane
        float mx = st[0][0];
        #pragma unroll
        for (int t = 0; t < 2; ++t)
            #pragma unroll
            for (int r = 0; r < 16; ++r) mx = fmaxf(mx, st[t][r]);
        mx = fmaxf(mx, __shfl_xor(mx, 32));

        if (!__all(mx <= m_run + 8.f)) {
            const float m_new = fmaxf(m_run, mx);
            const float corr = __builtin_amdgcn_exp2f((m_run - m_new) * C2);
            l_run *= corr;
            #pragma unroll
            for (int t = 0; t < 2; ++t)
                #pragma unroll
                for (int r = 0; r < 16; ++r) o[t][r] *= corr;
            m_run = m_new;
        }
        const float nb = -m_run * C2;

        // exp2 + mask + pack into quads: quad qidx=4t+g covers kv = kv0+8*qidx+4*hi..+3
        unsigned int ql[8], qh[8];
        float ps = 0.f;
        #pragma unroll
        for (int t = 0; t < 2; ++t)
            #pragma unroll
            for (int g = 0; g < 4; ++g) {
                half2 pa = cvt_pk(
                    __builtin_amdgcn_exp2f(fmaf(st[t][4 * g + 0], C2, nb)),
                    __builtin_amdgcn_exp2f(fmaf(st[t][4 * g + 1], C2, nb)));
                half2 pb = cvt_pk(
                    __builtin_amdgcn_exp2f(fmaf(st[t][4 * g + 2], C2, nb)),
                    __builtin_amdgcn_exp2f(fmaf(st[t][4 * g + 3], C2, nb)));
                const int base = kv0 + t * 32 + 8 * g + 4 * hi;
                const half4 mv = *(const half4*)(Mh + base);
                const half2 mk0 = { mv[0], mv[1] };
                const half2 mk1 = { mv[2], mv[3] };
                pa *= mk0;
                pb *= mk1;
                ps = fdot2_acc(pa, one2, ps);
                ps = fdot2_acc(pb, one2, ps);
                ql[4 * t + g] = __builtin_bit_cast(unsigned int, pa);
                qh[4 * t + g] = __builtin_bit_cast(unsigned int, pb);
            }
        ps += __shfl_xor(ps, 32);
        l_run += ps;

        // PV: B-frag[ks] needs kv = ks*16 + hi*8 + 0..7 = [quad, quad+4];
        // own quad = [2ks+hi], partner quad obtained by sending quad[2ks+hi^1].
        __builtin_amdgcn_s_setprio(1);
        #pragma unroll
        for (int ks = 0; ks < 4; ++ks) {
            const unsigned int sl = hi ? ql[2 * ks] : ql[2 * ks + 1];
            const unsigned int sh = hi ? qh[2 * ks] : qh[2 * ks + 1];
            const unsigned int rl = __shfl_xor(sl, 32);
            const unsigned int rh = __shfl_xor(sh, 32);
            union { unsigned int u[4]; half8 v; } bf;
            bf.u[0] = hi ? rl : ql[2 * ks];
            bf.u[1] = hi ? rh : qh[2 * ks];
            bf.u[2] = hi ? ql[2 * ks + 1] : rl;
            bf.u[3] = hi ? qh[2 * ks + 1] : rh;
            const half8 a0 = *(const half8*)(Vb + l31 * 72 + ks * 16 + hi * 8);
            const half8 a1 = *(const half8*)(Vb + (l31 + 32) * 72 + ks * 16 + hi * 8);
            o[0] = __builtin_amdgcn_mfma_f32_32x32x16_f16(a0, bf.v, o[0], 0, 0, 0);
            o[1] = __builtin_amdgcn_mfma_f32_32x32x16_f16(a1, bf.v, o[1], 0, 0, 0);
        }
        __builtin_amdgcn_s_setprio(0);
    };

    // register prefetch: tiles 0 (A regs) and 1 (B regs)
    uint4 ka0, ka1, va0, va1, kb0, kb1, vb0, vb1;
    ka0 = *(const uint4*)(Kg);            ka1 = *(const uint4*)(Kg + 8);
    va0 = *(const uint4*)(Vg);            va1 = *(const uint4*)(Vg + 8);
    kb0 = *(const uint4*)(Kg + 64 * 768); kb1 = *(const uint4*)(Kg + 64 * 768 + 8);
    vb0 = *(const uint4*)(Vg + 64);       vb1 = *(const uint4*)(Vg + 64 + 8);

    for (int j = 0; j < 8; ++j) {
        // ---- step 2j (buf A) ----
        *(uint4*)(KA + sr * 72 + sc)     = ka0;
        *(uint4*)(KA + sr * 72 + sc + 8) = ka1;
        *(uint4*)(VA + sr * 72 + sc)     = va0;
        *(uint4*)(VA + sr * 72 + sc + 8) = va1;
        if (j < 7) {
            const int t = (2 * j + 2) * 64;
            ka0 = *(const uint4*)(Kg + t * 768);
            ka1 = *(const uint4*)(Kg + t * 768 + 8);
            va0 = *(const uint4*)(Vg + t);
            va1 = *(const uint4*)(Vg + t + 8);
        }
        __syncthreads();
        compute(2 * j * 64, KA, VA);

        // ---- step 2j+1 (buf B) ----
        *(uint4*)(KB + sr * 72 + sc)     = kb0;
        *(uint4*)(KB + sr * 72 + sc + 8) = kb1;
        *(uint4*)(VB + sr * 72 + sc)     = vb0;
        *(uint4*)(VB + sr * 72 + sc + 8) = vb1;
        if (j < 7) {
            const int t = (2 * j + 3) * 64;
            kb0 = *(const uint4*)(Kg + t * 768);
            kb1 = *(const uint4*)(Kg + t * 768 + 8);
            vb0 = *(const uint4*)(Vg + t);
            vb1 = *(const uint4*)(Vg + t + 8);
        }
        __syncthreads();
        compute((2 * j + 1) * 64, KB, VB);
    }

    // epilogue: O^T col q = l31, row dv = 8g + 4hi + {0..3} + 32*dt
    const float inv = 1.f / l_run;
    const int qrow = b * 1024 + q0 + wave * 32 + l31;
    float* od = out + qrow * 768 + h * 64 + 4 * hi;
    #pragma unroll
    for (int dt = 0; dt < 2; ++dt)
        #pragma unroll
        for (int g = 0; g < 4; ++g) {
            float4 v;
            v.x = o[dt][4 * g + 0] * inv;
            v.y = o[dt][4 * g + 1] * inv;
            v.z = o[dt][4 * g + 2] * inv;
            v.w = o[dt][4 * g + 3] * inv;
            *(float4*)(od + dt * 32 + 8 * g) = v;
        }
}

extern "C" void kernel_launch(void* const* d_in, const int* in_sizes, int n_in,
                              void* d_out, int out_size, void* d_ws, size_t ws_size,
                              hipStream_t stream)
{
    const float* x  = (const float*)d_in[0];
    const float* y  = (const float*)d_in[1];
    const unsigned char* ym = (const unsigned char*)d_in[2];
    const float* Wq = (const float*)d_in[3];
    const float* bq = (const float*)d_in[4];
    const float* Wk = (const float*)d_in[5];
    const float* bk = (const float*)d_in[6];
    const float* Wv = (const float*)d_in[7];
    const float* bv = (const float*)d_in[8];

    _Float16* kws = (_Float16*)d_ws;             // [8192][768] K
    _Float16* vws = kws + 8192 * 768;            // [B][H*DV][L2] V^T
    _Float16* wt  = vws + 8192 * 768;            // [3][768][768] W^T (q,k,v)
    _Float16* qws = wt + 3 * 768 * 768;          // [8192][768] Q (optional)

    const size_t need = (size_t)(3 * 8192 * 768 + 3 * 768 * 768) * sizeof(_Float16);
    const bool qpre = ws_size >= need;

    wtrans_kernel<<<dim3(24, 24, 3), 256, 0, stream>>>(Wq, Wk, Wv, wt);
    projKV_kernel<<<768, 256, 0, stream>>>(y, wt, bk, bv, kws, vws);
    if (qpre) {
        projQ_kernel<<<384, 256, 0, stream>>>(x, wt, bq, qws);
        attn_kernel<true><<<768, 256, 0, stream>>>(
            x, wt, bq, qws, kws, vws, ym, (float*)d_out);
    } else {
        attn_kernel<false><<<768, 256, 0, stream>>>(
            x, wt, bq, qws, kws, vws, ym, (float*)d_out);
    }
}